// Round 13
// baseline (347.834 us; speedup 1.0000x reference)
//
#include <hip/hip_runtime.h>

#define F_IN 165
#define KP_PROJ 168
constexpr float NEG_SLOPE = 0.2f;

// ---- weight transposes + va vectors (va[i][k], i = plane*4+head) -----------
__global__ void k_trans(const float* __restrict__ pw, const float* __restrict__ w2,
                        const float* __restrict__ w1, const float* __restrict__ as1w,
                        const float* __restrict__ ad1w,
                        float* __restrict__ t0, float* __restrict__ t2,
                        float* __restrict__ va) {
    int i = blockIdx.x * 256 + threadIdx.x;
    const int n0 = 64 * KP_PROJ, n2 = 64 * 256;
    if (i < n0) {
        int c = i / KP_PROJ, r = i - c * KP_PROJ;
        t0[i] = (r < F_IN) ? pw[r * 64 + c] : 0.f;
    } else if (i < n0 + n2) {
        int j = i - n0; int c = j >> 8, r = j & 255;
        t2[j] = w2[r * 64 + c];
    } else if (i < n0 + n2 + 512) {
        int j = i - n0 - n2;          // 0..511
        int i2 = j >> 6;              // 0..7 = plane*4 + h
        int plane = i2 >> 2, h = i2 & 3, k = j & 63;
        const float* att = plane ? ad1w : as1w;
        float acc = 0.f;
        for (int c = 0; c < 64; ++c)
            acc = fmaf(w1[k * 256 + h * 64 + c], att[h * 64 + c], acc);
        va[j] = acc;
    }
}

// ---- h0 = relu(x @ W + b): Wt[64][168], 32 nodes/block, 4 groups x 8 nodes --
__global__ void k_proj(const float* __restrict__ x, const float* __restrict__ Wt,
                       const float* __restrict__ b, float* __restrict__ h0, int N) {
    __shared__ float xs[32][KP_PROJ];
    int base = blockIdx.x * 32;
    int t = threadIdx.x;
    for (int idx = t; idx < 32 * KP_PROJ; idx += 256) {
        int nl = idx / KP_PROJ, k = idx - nl * KP_PROJ;
        int node = base + nl;
        xs[nl][k] = (node < N && k < F_IN) ? x[(size_t)node * F_IN + k] : 0.f;
    }
    __syncthreads();
    int g = t >> 6, col = t & 63;
    float acc[8];
    float bb = b[col];
#pragma unroll
    for (int m = 0; m < 8; ++m) acc[m] = bb;
    const float* wrow = Wt + col * KP_PROJ;
    for (int k4 = 0; k4 < KP_PROJ / 4; ++k4) {
        float4 wv = *(const float4*)(wrow + k4 * 4);
#pragma unroll
        for (int m = 0; m < 8; ++m) {
            float4 av = *(const float4*)&xs[g * 8 + m][k4 * 4];
            acc[m] = fmaf(av.x, wv.x, acc[m]);
            acc[m] = fmaf(av.y, wv.y, acc[m]);
            acc[m] = fmaf(av.z, wv.z, acc[m]);
            acc[m] = fmaf(av.w, wv.w, acc[m]);
        }
    }
#pragma unroll
    for (int m = 0; m < 8; ++m) {
        int node = base + g * 8 + m;
        if (node < N) h0[(size_t)node * 64 + col] = fmaxf(acc[m], 0.f);
    }
}

// ---- as1/ad1 from h0 via va vectors: wave per node --------------------------
__global__ void k_attv1(const float* __restrict__ h0, const float* __restrict__ va,
                        float* __restrict__ as_, float* __restrict__ ad_, int N) {
    int t = threadIdx.x, lane = t & 63, wv = t >> 6;
    int n = blockIdx.x * 4 + wv;
    if (n >= N) return;
    float hv = h0[(size_t)n * 64 + lane];
    float r0 = hv * va[0 * 64 + lane], r1 = hv * va[1 * 64 + lane];
    float r2 = hv * va[2 * 64 + lane], r3 = hv * va[3 * 64 + lane];
    float r4 = hv * va[4 * 64 + lane], r5 = hv * va[5 * 64 + lane];
    float r6 = hv * va[6 * 64 + lane], r7 = hv * va[7 * 64 + lane];
#pragma unroll
    for (int off = 32; off; off >>= 1) {
        r0 += __shfl_xor(r0, off, 64); r1 += __shfl_xor(r1, off, 64);
        r2 += __shfl_xor(r2, off, 64); r3 += __shfl_xor(r3, off, 64);
        r4 += __shfl_xor(r4, off, 64); r5 += __shfl_xor(r5, off, 64);
        r6 += __shfl_xor(r6, off, 64); r7 += __shfl_xor(r7, off, 64);
    }
    if (lane == 0) {
        *(float4*)(as_ + (size_t)n * 4) = make_float4(r0, r1, r2, r3);
        *(float4*)(ad_ + (size_t)n * 4) = make_float4(r4, r5, r6, r7);
    }
}

// ---- h2lin = h1 @ W2: Wt2[64][256], 32 nodes/block, 4 groups x 8, fused att -
__global__ void k_lin2(const float* __restrict__ h1, const float* __restrict__ Wt,
                       const float* __restrict__ att_s, const float* __restrict__ att_d,
                       float* __restrict__ out, float* __restrict__ as_,
                       float* __restrict__ ad_, int N) {
    __shared__ float hs[32][256];
    int base = blockIdx.x * 32;
    int t = threadIdx.x;
    for (int i = 0; i < 8; ++i) {
        int idx4 = t + i * 256;
        int nl = idx4 >> 6, k4 = idx4 & 63;
        int node = base + nl;
        float4 v = make_float4(0.f, 0.f, 0.f, 0.f);
        if (node < N) v = *(const float4*)(h1 + (size_t)node * 256 + k4 * 4);
        *(float4*)&hs[nl][k4 * 4] = v;
    }
    __syncthreads();
    int g = t >> 6, col = t & 63;
    float acc[8] = {};
    const float* wrow = Wt + col * 256;
    for (int k4 = 0; k4 < 64; ++k4) {
        float4 wv = *(const float4*)(wrow + k4 * 4);
#pragma unroll
        for (int m = 0; m < 8; ++m) {
            float4 av = *(const float4*)&hs[g * 8 + m][k4 * 4];
            acc[m] = fmaf(av.x, wv.x, acc[m]);
            acc[m] = fmaf(av.y, wv.y, acc[m]);
            acc[m] = fmaf(av.z, wv.z, acc[m]);
            acc[m] = fmaf(av.w, wv.w, acc[m]);
        }
    }
    float sw = att_s[col], dw = att_d[col];
#pragma unroll
    for (int m = 0; m < 8; ++m) {
        int node = base + g * 8 + m;
        if (node < N) out[(size_t)node * 64 + col] = acc[m];
        float sv = acc[m] * sw, dv = acc[m] * dw;
#pragma unroll
        for (int off = 32; off; off >>= 1) {
            sv += __shfl_xor(sv, off, 64);
            dv += __shfl_xor(dv, off, 64);
        }
        if (col == 0 && node < N) { as_[node] = sv; ad_[node] = dv; }
    }
}

// ------- CSR build over REAL edges only (self-loops handled inline) ----------
__global__ void k_deg(const int* __restrict__ ei, int E, int* __restrict__ deg) {
    for (int i = blockIdx.x * blockDim.x + threadIdx.x; i < E; i += gridDim.x * blockDim.x) {
        atomicAdd(&deg[ei[E + i]], 1);
    }
}

__global__ void k_scan_part(const int* __restrict__ deg, int* __restrict__ out,
                            int* __restrict__ partials, int n) {
    __shared__ int tmp[1024];
    int b = blockIdx.x, t = threadIdx.x;
    int i = b * 1024 + t;
    int v = (i < n) ? deg[i] : 0;
    tmp[t] = v;
    __syncthreads();
    for (int off = 1; off < 1024; off <<= 1) {
        int xval = (t >= off) ? tmp[t - off] : 0;
        __syncthreads();
        tmp[t] += xval;
        __syncthreads();
    }
    if (i < n) out[i] = tmp[t] - v; // exclusive
    if (t == 1023) partials[b] = tmp[t];
}

__global__ void k_scan_small(int* __restrict__ partials, int nblk) {
    int lane = threadIdx.x & 63;
    int carry = 0;
    for (int base = 0; base < nblk; base += 64) {
        int idx = base + lane;
        int v = (idx < nblk) ? partials[idx] : 0;
        int orig = v;
#pragma unroll
        for (int off = 1; off < 64; off <<= 1) {
            int u = __shfl_up(v, off, 64);
            if (lane >= off) v += u;
        }
        if (idx < nblk) partials[idx] = carry + v - orig; // exclusive
        carry += __shfl(v, 63, 64);
    }
}

__global__ void k_scan_add(int* __restrict__ rowptr, const int* __restrict__ partials,
                           int n, int total) {
    int i = blockIdx.x * 1024 + threadIdx.x;
    if (i < n) rowptr[i] += partials[blockIdx.x];
    if (i == 0) rowptr[n] = total;
}

__global__ void k_scatter(const int* __restrict__ ei, int E,
                          const int* __restrict__ rowptr, int* __restrict__ cursor,
                          int* __restrict__ csrc) {
    for (int i = blockIdx.x * blockDim.x + threadIdx.x; i < E; i += gridDim.x * blockDim.x) {
        int src = ei[i], dst = ei[E + i];
        int pos = rowptr[dst] + atomicAdd(&cursor[dst], 1);
        csrc[pos] = src;
    }
}

// --------- GAT layer 1 fused: inline edge weights + h0 agg + W1 GEMM ---------
// Phase 1: wave per dst, 4 edge-slots x 16 lanes, self-loop seeded in slot 0.
// Staging buffer transposed to agg2[256][4] so phase 2 reads ONE ds_read_b128
// (wave-uniform broadcast) per k instead of 4 scalar LDS reads.
// Phase 2: scalar W1 reads (spill-safe codegen, r4/5/9) + unroll 4 (r11: never
// unroll 1, never let float4 global loads become fully-unrollable/hoistable).
__global__ void k_gat1f(const float* __restrict__ h0, const float* __restrict__ as1,
                        const float* __restrict__ ad1, const int* __restrict__ rowptr,
                        const int* __restrict__ csrc, const float* __restrict__ W1,
                        const float* __restrict__ b1, float* __restrict__ h1out, int N) {
    __shared__ float agg2[4][256][4];   // [wave][h*64+k][node-elem transposed]
    int t = threadIdx.x, wv = t >> 6, lane = t & 63;
    int slot = lane >> 4, sl = lane & 15;
    int d = blockIdx.x * 4 + wv;
    if (d < N) {
        int s0 = rowptr[d], e0 = rowptr[d + 1];
        float4 ad = *(const float4*)(ad1 + (size_t)d * 4);
        float a00=0,a01=0,a02=0,a03=0;
        float a10=0,a11=0,a12=0,a13=0;
        float a20=0,a21=0,a22=0,a23=0;
        float a30=0,a31=0,a32=0,a33=0;
        float d0=0,d1=0,d2=0,d3=0;
        const float* hb = h0 + sl * 4;
        if (slot == 0) {
            // self-loop: z = lrelu(as1[d]+ad1[d])
            float4 a = *(const float4*)(as1 + (size_t)d * 4);
            float z0 = a.x + ad.x, z1 = a.y + ad.y, z2 = a.z + ad.z, z3 = a.w + ad.w;
            z0 = (z0 > 0.f) ? z0 : NEG_SLOPE * z0;
            z1 = (z1 > 0.f) ? z1 : NEG_SLOPE * z1;
            z2 = (z2 > 0.f) ? z2 : NEG_SLOPE * z2;
            z3 = (z3 > 0.f) ? z3 : NEG_SLOPE * z3;
            float wx = __expf(z0), wy = __expf(z1), wz = __expf(z2), ww = __expf(z3);
            float4 hv = *(const float4*)(hb + (size_t)d * 64);
            a00 = wx*hv.x; a01 = wx*hv.y; a02 = wx*hv.z; a03 = wx*hv.w;
            a10 = wy*hv.x; a11 = wy*hv.y; a12 = wy*hv.z; a13 = wy*hv.w;
            a20 = wz*hv.x; a21 = wz*hv.y; a22 = wz*hv.z; a23 = wz*hv.w;
            a30 = ww*hv.x; a31 = ww*hv.y; a32 = ww*hv.z; a33 = ww*hv.w;
            d0 = wx; d1 = wy; d2 = wz; d3 = ww;
        }
        for (int j = s0 + slot; j < e0; j += 4) {
            int s = csrc[j];
            float4 a = *(const float4*)(as1 + (size_t)s * 4);
            float4 hv = *(const float4*)(hb + (size_t)s * 64);
            float z0 = a.x + ad.x, z1 = a.y + ad.y, z2 = a.z + ad.z, z3 = a.w + ad.w;
            z0 = (z0 > 0.f) ? z0 : NEG_SLOPE * z0;
            z1 = (z1 > 0.f) ? z1 : NEG_SLOPE * z1;
            z2 = (z2 > 0.f) ? z2 : NEG_SLOPE * z2;
            z3 = (z3 > 0.f) ? z3 : NEG_SLOPE * z3;
            float wx = __expf(z0), wy = __expf(z1), wz = __expf(z2), ww = __expf(z3);
            a00 = fmaf(wx, hv.x, a00); a01 = fmaf(wx, hv.y, a01);
            a02 = fmaf(wx, hv.z, a02); a03 = fmaf(wx, hv.w, a03);
            a10 = fmaf(wy, hv.x, a10); a11 = fmaf(wy, hv.y, a11);
            a12 = fmaf(wy, hv.z, a12); a13 = fmaf(wy, hv.w, a13);
            a20 = fmaf(wz, hv.x, a20); a21 = fmaf(wz, hv.y, a21);
            a22 = fmaf(wz, hv.z, a22); a23 = fmaf(wz, hv.w, a23);
            a30 = fmaf(ww, hv.x, a30); a31 = fmaf(ww, hv.y, a31);
            a32 = fmaf(ww, hv.z, a32); a33 = fmaf(ww, hv.w, a33);
            d0 += wx; d1 += wy; d2 += wz; d3 += ww;
        }
#pragma unroll
        for (int off = 16; off <= 32; off <<= 1) {
            a00 += __shfl_xor(a00, off, 64); a01 += __shfl_xor(a01, off, 64);
            a02 += __shfl_xor(a02, off, 64); a03 += __shfl_xor(a03, off, 64);
            a10 += __shfl_xor(a10, off, 64); a11 += __shfl_xor(a11, off, 64);
            a12 += __shfl_xor(a12, off, 64); a13 += __shfl_xor(a13, off, 64);
            a20 += __shfl_xor(a20, off, 64); a21 += __shfl_xor(a21, off, 64);
            a22 += __shfl_xor(a22, off, 64); a23 += __shfl_xor(a23, off, 64);
            a30 += __shfl_xor(a30, off, 64); a31 += __shfl_xor(a31, off, 64);
            a32 += __shfl_xor(a32, off, 64); a33 += __shfl_xor(a33, off, 64);
            d0  += __shfl_xor(d0,  off, 64); d1  += __shfl_xor(d1,  off, 64);
            d2  += __shfl_xor(d2,  off, 64); d3  += __shfl_xor(d3,  off, 64);
        }
        if (slot == 0) {
            float i0 = 1.f / d0, i1 = 1.f / d1, i2 = 1.f / d2, i3 = 1.f / d3;
            int kb = sl * 4;
            agg2[wv][  0 + kb][0] = a00*i0; agg2[wv][  0 + kb + 1][0] = a01*i0;
            agg2[wv][  0 + kb + 2][0] = a02*i0; agg2[wv][  0 + kb + 3][0] = a03*i0;
            agg2[wv][ 64 + kb][1] = a10*i1; agg2[wv][ 64 + kb + 1][1] = a11*i1;
            agg2[wv][ 64 + kb + 2][1] = a12*i1; agg2[wv][ 64 + kb + 3][1] = a13*i1;
            agg2[wv][128 + kb][2] = a20*i2; agg2[wv][128 + kb + 1][2] = a21*i2;
            agg2[wv][128 + kb + 2][2] = a22*i2; agg2[wv][128 + kb + 3][2] = a23*i2;
            agg2[wv][192 + kb][3] = a30*i3; agg2[wv][192 + kb + 1][3] = a31*i3;
            agg2[wv][192 + kb + 2][3] = a32*i3; agg2[wv][192 + kb + 3][3] = a33*i3;
        }
    }
    __syncthreads();
    // agg2[wv][h*64+k][e]: value for NODE wv... wait -- transpose is over heads?
    // Layout note: agg2[wv][i][e] holds head (i>>6), element k=(i&63) slice e for
    // wave wv's dst node, where e indexes the 4 ACC COLUMNS (a_h0..a_h3) -- i.e.
    // e is the head's 4-elem group. Phase 2 needs per (node, h, k). Re-derive:
    // slot-0 write above stores agg2[wv][h*64 + k][h'] where h' is the HEAD idx
    // of the accumulator quadruple -- a_h{e} is head h, elem (kb+e). Correct
    // mapping: agg2[wv][h*64 + kb + e][h] -- written as such above (row block
    // h*64, last index h). Phase-2 read below uses matching [h] index.
    int h = t >> 6;
    float o0 = 0.f, o1 = 0.f, o2 = 0.f, o3 = 0.f;
#pragma unroll 4
    for (int k = 0; k < 64; ++k) {
        float wv1 = W1[k * 256 + t];
        o0 = fmaf(agg2[0][h * 64 + k][h], wv1, o0);
        o1 = fmaf(agg2[1][h * 64 + k][h], wv1, o1);
        o2 = fmaf(agg2[2][h * 64 + k][h], wv1, o2);
        o3 = fmaf(agg2[3][h * 64 + k][h], wv1, o3);
    }
    float bb = b1[t];
    int base = blockIdx.x * 4;
    if (base + 0 < N) h1out[(size_t)(base + 0) * 256 + t] = fmaxf(o0 + bb, 0.f);
    if (base + 1 < N) h1out[(size_t)(base + 1) * 256 + t] = fmaxf(o1 + bb, 0.f);
    if (base + 2 < N) h1out[(size_t)(base + 2) * 256 + t] = fmaxf(o2 + bb, 0.f);
    if (base + 3 < N) h1out[(size_t)(base + 3) * 256 + t] = fmaxf(o3 + bb, 0.f);
}

// --------- GAT layer 2 (1 head): wave per dst, inline weights + classifier ---
__global__ void k_gat2(const float* __restrict__ hlin, const float* __restrict__ as2,
                       const float* __restrict__ ad2, const int* __restrict__ rowptr,
                       const int* __restrict__ csrc, const float* __restrict__ bias,
                       const float* __restrict__ clsW, const float* __restrict__ clsB,
                       float* __restrict__ out, int N) {
    int t = threadIdx.x, wv = t >> 6, lane = t & 63;
    int slot = lane >> 4, sl = lane & 15;
    int d = blockIdx.x * 4 + wv;
    if (d >= N) return;
    int s0 = rowptr[d], e0 = rowptr[d + 1];
    float add = ad2[d];
    float ax = 0.f, ay = 0.f, az = 0.f, aw = 0.f, den = 0.f;
    const float* hb = hlin + sl * 4;
    if (slot == 0) {   // self-loop
        float z = as2[d] + add;
        z = (z > 0.f) ? z : NEG_SLOPE * z;
        float w = __expf(z);
        float4 hv = *(const float4*)(hb + (size_t)d * 64);
        ax = w * hv.x; ay = w * hv.y; az = w * hv.z; aw = w * hv.w;
        den = w;
    }
    for (int j = s0 + slot; j < e0; j += 4) {
        int s = csrc[j];
        float z = as2[s] + add;
        z = (z > 0.f) ? z : NEG_SLOPE * z;
        float w = __expf(z);
        float4 hv = *(const float4*)(hb + (size_t)s * 64);
        ax = fmaf(w, hv.x, ax); ay = fmaf(w, hv.y, ay);
        az = fmaf(w, hv.z, az); aw = fmaf(w, hv.w, aw);
        den += w;
    }
#pragma unroll
    for (int off = 16; off <= 32; off <<= 1) {
        ax += __shfl_xor(ax, off, 64); ay += __shfl_xor(ay, off, 64);
        az += __shfl_xor(az, off, 64); aw += __shfl_xor(aw, off, 64);
        den += __shfl_xor(den, off, 64);
    }
    float inv = 1.f / den;
    float4 bb = *(const float4*)(bias + sl * 4);
    float4 cw = *(const float4*)(clsW + sl * 4);
    float p = fmaxf(fmaf(ax, inv, bb.x), 0.f) * cw.x
            + fmaxf(fmaf(ay, inv, bb.y), 0.f) * cw.y
            + fmaxf(fmaf(az, inv, bb.z), 0.f) * cw.z
            + fmaxf(fmaf(aw, inv, bb.w), 0.f) * cw.w;
#pragma unroll
    for (int off = 1; off <= 8; off <<= 1) p += __shfl_xor(p, off, 64);
    if (lane == 0) out[d] = p + clsB[0];
}

extern "C" void kernel_launch(void* const* d_in, const int* in_sizes, int n_in,
                              void* d_out, int out_size, void* d_ws, size_t ws_size,
                              hipStream_t stream) {
    const float* x     = (const float*)d_in[0];
    const int*   ei    = (const int*)d_in[1];
    const float* projW = (const float*)d_in[2];
    const float* projB = (const float*)d_in[3];
    const float* W1    = (const float*)d_in[4];
    const float* as1w  = (const float*)d_in[5];
    const float* ad1w  = (const float*)d_in[6];
    const float* b1    = (const float*)d_in[7];
    const float* W2    = (const float*)d_in[8];
    const float* as2w  = (const float*)d_in[9];
    const float* ad2w  = (const float*)d_in[10];
    const float* b2    = (const float*)d_in[11];
    const float* clsW  = (const float*)d_in[12];
    const float* clsB  = (const float*)d_in[13];
    float* out = (float*)d_out;

    const int N = in_sizes[0] / F_IN;
    const int E = in_sizes[1] / 2;

    char* ws = (char*)d_ws;
    size_t off = 0;
    auto alloc = [&](size_t bytes) -> void* {
        void* p = ws + off;
        off += (bytes + 255) & ~(size_t)255;
        return p;
    };
    float* h0     = (float*)alloc((size_t)N * 64 * 4);   // reused as h2lin
    float* h1     = (float*)alloc((size_t)N * 256 * 4);
    float* as1    = (float*)alloc((size_t)N * 4 * 4);
    float* ad1    = (float*)alloc((size_t)N * 4 * 4);
    float* as2    = (float*)alloc((size_t)N * 4);
    float* ad2    = (float*)alloc((size_t)N * 4);
    int*   dc     = (int*)alloc((size_t)2 * N * 4);      // deg | cursor adjacent
    int*   deg    = dc;
    int*   cursor = dc + N;
    int*   rowptr = (int*)alloc((size_t)(N + 1) * 4);
    int*   parts  = (int*)alloc(1024 * 4);
    int*   csrc   = (int*)alloc((size_t)E * 4);
    float* wt0    = (float*)alloc(64 * KP_PROJ * 4);
    float* wt2    = (float*)alloc(64 * 256 * 4);
    float* va     = (float*)alloc(512 * 4);
    float* h2lin  = h0;

    // weight transposes + va vectors
    k_trans<<<(64 * KP_PROJ + 64 * 256 + 512 + 255) / 256, 256, 0, stream>>>(
        projW, W2, W1, as1w, ad1w, wt0, wt2, va);

    // CSR build (real edges only; self-loops inline in aggregation kernels)
    hipMemsetAsync(dc, 0, (size_t)2 * N * 4, stream);
    k_deg<<<1024, 256, 0, stream>>>(ei, E, deg);
    int nblk = (N + 1023) / 1024;
    k_scan_part<<<nblk, 1024, 0, stream>>>(deg, rowptr, parts, N);
    k_scan_small<<<1, 64, 0, stream>>>(parts, nblk);
    k_scan_add<<<nblk, 1024, 0, stream>>>(rowptr, parts, N, E);
    k_scatter<<<1024, 256, 0, stream>>>(ei, E, rowptr, cursor, csrc);

    // MLP in
    k_proj<<<(N + 31) / 32, 256, 0, stream>>>(x, wt0, projB, h0, N);

    // GAT layer 1 (h0-domain aggregation, edge weights inline)
    k_attv1<<<(N + 3) / 4, 256, 0, stream>>>(h0, va, as1, ad1, N);
    k_gat1f<<<(N + 3) / 4, 256, 0, stream>>>(h0, as1, ad1, rowptr, csrc, W1, b1, h1, N);

    // GAT layer 2 + classifier (edge weights fused into k_gat2)
    k_lin2<<<(N + 31) / 32, 256, 0, stream>>>(h1, wt2, as2w, ad2w, h2lin, as2, ad2, N);
    k_gat2<<<(N + 3) / 4, 256, 0, stream>>>(h2lin, as2, ad2, rowptr, csrc, b2,
                                            clsW, clsB, out, N);
}

// Round 14
// 336.015 us; speedup vs baseline: 1.0352x; 1.0352x over previous
//
#include <hip/hip_runtime.h>

#define F_IN 165
#define KP_PROJ 168
constexpr float NEG_SLOPE = 0.2f;

// ---- weight transposes + va vectors (va[i][k], i = plane*4+head) -----------
__global__ void k_trans(const float* __restrict__ pw, const float* __restrict__ w2,
                        const float* __restrict__ w1, const float* __restrict__ as1w,
                        const float* __restrict__ ad1w,
                        float* __restrict__ t0, float* __restrict__ t2,
                        float* __restrict__ va) {
    int i = blockIdx.x * 256 + threadIdx.x;
    const int n0 = 64 * KP_PROJ, n2 = 64 * 256;
    if (i < n0) {
        int c = i / KP_PROJ, r = i - c * KP_PROJ;
        t0[i] = (r < F_IN) ? pw[r * 64 + c] : 0.f;
    } else if (i < n0 + n2) {
        int j = i - n0; int c = j >> 8, r = j & 255;
        t2[j] = w2[r * 64 + c];
    } else if (i < n0 + n2 + 512) {
        int j = i - n0 - n2;          // 0..511
        int i2 = j >> 6;              // 0..7 = plane*4 + h
        int plane = i2 >> 2, h = i2 & 3, k = j & 63;
        const float* att = plane ? ad1w : as1w;
        float acc = 0.f;
        for (int c = 0; c < 64; ++c)
            acc = fmaf(w1[k * 256 + h * 64 + c], att[h * 64 + c], acc);
        va[j] = acc;
    }
}

// ---- h0 = relu(x @ W + b) + fused as1/ad1 attention reduction ---------------
// Wt[64][168], 32 nodes/block, 4 waves x 8 nodes. After the GEMM, each wave
// reduces its 8 nodes' h0 values against the 8 va vectors in-register
// (same fused-att pattern as k_lin2) -- deletes the separate k_attv1 pass.
__global__ void k_proj(const float* __restrict__ x, const float* __restrict__ Wt,
                       const float* __restrict__ b, const float* __restrict__ va,
                       float* __restrict__ h0, float* __restrict__ as_,
                       float* __restrict__ ad_, int N) {
    __shared__ float xs[32][KP_PROJ];
    int base = blockIdx.x * 32;
    int t = threadIdx.x;
    for (int idx = t; idx < 32 * KP_PROJ; idx += 256) {
        int nl = idx / KP_PROJ, k = idx - nl * KP_PROJ;
        int node = base + nl;
        xs[nl][k] = (node < N && k < F_IN) ? x[(size_t)node * F_IN + k] : 0.f;
    }
    __syncthreads();
    int g = t >> 6, col = t & 63;
    float acc[8];
    float bb = b[col];
#pragma unroll
    for (int m = 0; m < 8; ++m) acc[m] = bb;
    const float* wrow = Wt + col * KP_PROJ;
    for (int k4 = 0; k4 < KP_PROJ / 4; ++k4) {
        float4 wv = *(const float4*)(wrow + k4 * 4);
#pragma unroll
        for (int m = 0; m < 8; ++m) {
            float4 av = *(const float4*)&xs[g * 8 + m][k4 * 4];
            acc[m] = fmaf(av.x, wv.x, acc[m]);
            acc[m] = fmaf(av.y, wv.y, acc[m]);
            acc[m] = fmaf(av.z, wv.z, acc[m]);
            acc[m] = fmaf(av.w, wv.w, acc[m]);
        }
    }
    float v0 = va[0 * 64 + col], v1 = va[1 * 64 + col];
    float v2 = va[2 * 64 + col], v3 = va[3 * 64 + col];
    float v4 = va[4 * 64 + col], v5 = va[5 * 64 + col];
    float v6 = va[6 * 64 + col], v7 = va[7 * 64 + col];
#pragma unroll
    for (int m = 0; m < 8; ++m) {
        int node = base + g * 8 + m;
        float h = fmaxf(acc[m], 0.f);
        if (node < N) h0[(size_t)node * 64 + col] = h;
        float r0 = h * v0, r1 = h * v1, r2 = h * v2, r3 = h * v3;
        float r4 = h * v4, r5 = h * v5, r6 = h * v6, r7 = h * v7;
#pragma unroll
        for (int off = 32; off; off >>= 1) {
            r0 += __shfl_xor(r0, off, 64); r1 += __shfl_xor(r1, off, 64);
            r2 += __shfl_xor(r2, off, 64); r3 += __shfl_xor(r3, off, 64);
            r4 += __shfl_xor(r4, off, 64); r5 += __shfl_xor(r5, off, 64);
            r6 += __shfl_xor(r6, off, 64); r7 += __shfl_xor(r7, off, 64);
        }
        if (col == 0 && node < N) {
            *(float4*)(as_ + (size_t)node * 4) = make_float4(r0, r1, r2, r3);
            *(float4*)(ad_ + (size_t)node * 4) = make_float4(r4, r5, r6, r7);
        }
    }
}

// ---- h2lin = h1 @ W2: Wt2[64][256], 32 nodes/block, 4 groups x 8, fused att -
__global__ void k_lin2(const float* __restrict__ h1, const float* __restrict__ Wt,
                       const float* __restrict__ att_s, const float* __restrict__ att_d,
                       float* __restrict__ out, float* __restrict__ as_,
                       float* __restrict__ ad_, int N) {
    __shared__ float hs[32][256];
    int base = blockIdx.x * 32;
    int t = threadIdx.x;
    for (int i = 0; i < 8; ++i) {
        int idx4 = t + i * 256;
        int nl = idx4 >> 6, k4 = idx4 & 63;
        int node = base + nl;
        float4 v = make_float4(0.f, 0.f, 0.f, 0.f);
        if (node < N) v = *(const float4*)(h1 + (size_t)node * 256 + k4 * 4);
        *(float4*)&hs[nl][k4 * 4] = v;
    }
    __syncthreads();
    int g = t >> 6, col = t & 63;
    float acc[8] = {};
    const float* wrow = Wt + col * 256;
    for (int k4 = 0; k4 < 64; ++k4) {
        float4 wv = *(const float4*)(wrow + k4 * 4);
#pragma unroll
        for (int m = 0; m < 8; ++m) {
            float4 av = *(const float4*)&hs[g * 8 + m][k4 * 4];
            acc[m] = fmaf(av.x, wv.x, acc[m]);
            acc[m] = fmaf(av.y, wv.y, acc[m]);
            acc[m] = fmaf(av.z, wv.z, acc[m]);
            acc[m] = fmaf(av.w, wv.w, acc[m]);
        }
    }
    float sw = att_s[col], dw = att_d[col];
#pragma unroll
    for (int m = 0; m < 8; ++m) {
        int node = base + g * 8 + m;
        if (node < N) out[(size_t)node * 64 + col] = acc[m];
        float sv = acc[m] * sw, dv = acc[m] * dw;
#pragma unroll
        for (int off = 32; off; off >>= 1) {
            sv += __shfl_xor(sv, off, 64);
            dv += __shfl_xor(dv, off, 64);
        }
        if (col == 0 && node < N) { as_[node] = sv; ad_[node] = dv; }
    }
}

// ------- CSR build over REAL edges only (self-loops handled inline) ----------
__global__ void k_deg(const int* __restrict__ ei, int E, int* __restrict__ deg) {
    for (int i = blockIdx.x * blockDim.x + threadIdx.x; i < E; i += gridDim.x * blockDim.x) {
        atomicAdd(&deg[ei[E + i]], 1);
    }
}

__global__ void k_scan_part(const int* __restrict__ deg, int* __restrict__ out,
                            int* __restrict__ partials, int n) {
    __shared__ int tmp[1024];
    int b = blockIdx.x, t = threadIdx.x;
    int i = b * 1024 + t;
    int v = (i < n) ? deg[i] : 0;
    tmp[t] = v;
    __syncthreads();
    for (int off = 1; off < 1024; off <<= 1) {
        int xval = (t >= off) ? tmp[t - off] : 0;
        __syncthreads();
        tmp[t] += xval;
        __syncthreads();
    }
    if (i < n) out[i] = tmp[t] - v; // exclusive
    if (t == 1023) partials[b] = tmp[t];
}

__global__ void k_scan_small(int* __restrict__ partials, int nblk) {
    int lane = threadIdx.x & 63;
    int carry = 0;
    for (int base = 0; base < nblk; base += 64) {
        int idx = base + lane;
        int v = (idx < nblk) ? partials[idx] : 0;
        int orig = v;
#pragma unroll
        for (int off = 1; off < 64; off <<= 1) {
            int u = __shfl_up(v, off, 64);
            if (lane >= off) v += u;
        }
        if (idx < nblk) partials[idx] = carry + v - orig; // exclusive
        carry += __shfl(v, 63, 64);
    }
}

__global__ void k_scan_add(int* __restrict__ rowptr, const int* __restrict__ partials,
                           int n, int total) {
    int i = blockIdx.x * 1024 + threadIdx.x;
    if (i < n) rowptr[i] += partials[blockIdx.x];
    if (i == 0) rowptr[n] = total;
}

__global__ void k_scatter(const int* __restrict__ ei, int E,
                          const int* __restrict__ rowptr, int* __restrict__ cursor,
                          int* __restrict__ csrc) {
    for (int i = blockIdx.x * blockDim.x + threadIdx.x; i < E; i += gridDim.x * blockDim.x) {
        int src = ei[i], dst = ei[E + i];
        int pos = rowptr[dst] + atomicAdd(&cursor[dst], 1);
        csrc[pos] = src;
    }
}

// --------- GAT layer 1 fused: inline edge weights + h0 agg + W1 GEMM ---------
// Phase 1: wave per dst, 4 edge-slots x 16 lanes, self-loop seeded in slot 0.
// Staging: agg[4][256] (r12 proven; r13's transposed [256][4] layout caused
// 5.6M LDS write bank conflicts -- do not reintroduce).
// Phase 2: scalar W1 + scalar LDS reads (r10/r12 proven codegen). Do NOT
// vectorize (spills, r4/5/9), pin unroll 1 (slower, r11), or transpose (r13).
__global__ void k_gat1f(const float* __restrict__ h0, const float* __restrict__ as1,
                        const float* __restrict__ ad1, const int* __restrict__ rowptr,
                        const int* __restrict__ csrc, const float* __restrict__ W1,
                        const float* __restrict__ b1, float* __restrict__ h1out, int N) {
    __shared__ float agg[4][256];
    int t = threadIdx.x, wv = t >> 6, lane = t & 63;
    int slot = lane >> 4, sl = lane & 15;
    int d = blockIdx.x * 4 + wv;
    if (d < N) {
        int s0 = rowptr[d], e0 = rowptr[d + 1];
        float4 ad = *(const float4*)(ad1 + (size_t)d * 4);
        float a00=0,a01=0,a02=0,a03=0;
        float a10=0,a11=0,a12=0,a13=0;
        float a20=0,a21=0,a22=0,a23=0;
        float a30=0,a31=0,a32=0,a33=0;
        float d0=0,d1=0,d2=0,d3=0;
        const float* hb = h0 + sl * 4;
        if (slot == 0) {
            // self-loop
            float4 a = *(const float4*)(as1 + (size_t)d * 4);
            float z0 = a.x + ad.x, z1 = a.y + ad.y, z2 = a.z + ad.z, z3 = a.w + ad.w;
            z0 = (z0 > 0.f) ? z0 : NEG_SLOPE * z0;
            z1 = (z1 > 0.f) ? z1 : NEG_SLOPE * z1;
            z2 = (z2 > 0.f) ? z2 : NEG_SLOPE * z2;
            z3 = (z3 > 0.f) ? z3 : NEG_SLOPE * z3;
            float wx = __expf(z0), wy = __expf(z1), wz = __expf(z2), ww = __expf(z3);
            float4 hv = *(const float4*)(hb + (size_t)d * 64);
            a00 = wx*hv.x; a01 = wx*hv.y; a02 = wx*hv.z; a03 = wx*hv.w;
            a10 = wy*hv.x; a11 = wy*hv.y; a12 = wy*hv.z; a13 = wy*hv.w;
            a20 = wz*hv.x; a21 = wz*hv.y; a22 = wz*hv.z; a23 = wz*hv.w;
            a30 = ww*hv.x; a31 = ww*hv.y; a32 = ww*hv.z; a33 = ww*hv.w;
            d0 = wx; d1 = wy; d2 = wz; d3 = ww;
        }
        for (int j = s0 + slot; j < e0; j += 4) {
            int s = csrc[j];
            float4 a = *(const float4*)(as1 + (size_t)s * 4);
            float4 hv = *(const float4*)(hb + (size_t)s * 64);
            float z0 = a.x + ad.x, z1 = a.y + ad.y, z2 = a.z + ad.z, z3 = a.w + ad.w;
            z0 = (z0 > 0.f) ? z0 : NEG_SLOPE * z0;
            z1 = (z1 > 0.f) ? z1 : NEG_SLOPE * z1;
            z2 = (z2 > 0.f) ? z2 : NEG_SLOPE * z2;
            z3 = (z3 > 0.f) ? z3 : NEG_SLOPE * z3;
            float wx = __expf(z0), wy = __expf(z1), wz = __expf(z2), ww = __expf(z3);
            a00 = fmaf(wx, hv.x, a00); a01 = fmaf(wx, hv.y, a01);
            a02 = fmaf(wx, hv.z, a02); a03 = fmaf(wx, hv.w, a03);
            a10 = fmaf(wy, hv.x, a10); a11 = fmaf(wy, hv.y, a11);
            a12 = fmaf(wy, hv.z, a12); a13 = fmaf(wy, hv.w, a13);
            a20 = fmaf(wz, hv.x, a20); a21 = fmaf(wz, hv.y, a21);
            a22 = fmaf(wz, hv.z, a22); a23 = fmaf(wz, hv.w, a23);
            a30 = fmaf(ww, hv.x, a30); a31 = fmaf(ww, hv.y, a31);
            a32 = fmaf(ww, hv.z, a32); a33 = fmaf(ww, hv.w, a33);
            d0 += wx; d1 += wy; d2 += wz; d3 += ww;
        }
#pragma unroll
        for (int off = 16; off <= 32; off <<= 1) {
            a00 += __shfl_xor(a00, off, 64); a01 += __shfl_xor(a01, off, 64);
            a02 += __shfl_xor(a02, off, 64); a03 += __shfl_xor(a03, off, 64);
            a10 += __shfl_xor(a10, off, 64); a11 += __shfl_xor(a11, off, 64);
            a12 += __shfl_xor(a12, off, 64); a13 += __shfl_xor(a13, off, 64);
            a20 += __shfl_xor(a20, off, 64); a21 += __shfl_xor(a21, off, 64);
            a22 += __shfl_xor(a22, off, 64); a23 += __shfl_xor(a23, off, 64);
            a30 += __shfl_xor(a30, off, 64); a31 += __shfl_xor(a31, off, 64);
            a32 += __shfl_xor(a32, off, 64); a33 += __shfl_xor(a33, off, 64);
            d0  += __shfl_xor(d0,  off, 64); d1  += __shfl_xor(d1,  off, 64);
            d2  += __shfl_xor(d2,  off, 64); d3  += __shfl_xor(d3,  off, 64);
        }
        if (slot == 0) {
            float i0 = 1.f / d0, i1 = 1.f / d1, i2 = 1.f / d2, i3 = 1.f / d3;
            *(float4*)&agg[wv][  0 + sl * 4] = make_float4(a00*i0, a01*i0, a02*i0, a03*i0);
            *(float4*)&agg[wv][ 64 + sl * 4] = make_float4(a10*i1, a11*i1, a12*i1, a13*i1);
            *(float4*)&agg[wv][128 + sl * 4] = make_float4(a20*i2, a21*i2, a22*i2, a23*i2);
            *(float4*)&agg[wv][192 + sl * 4] = make_float4(a30*i3, a31*i3, a32*i3, a33*i3);
        }
    }
    __syncthreads();
    int h = t >> 6;
    float o0 = 0.f, o1 = 0.f, o2 = 0.f, o3 = 0.f;
    for (int k = 0; k < 64; ++k) {
        float wv1 = W1[k * 256 + t];
        o0 = fmaf(agg[0][h * 64 + k], wv1, o0);
        o1 = fmaf(agg[1][h * 64 + k], wv1, o1);
        o2 = fmaf(agg[2][h * 64 + k], wv1, o2);
        o3 = fmaf(agg[3][h * 64 + k], wv1, o3);
    }
    float bb = b1[t];
    int base = blockIdx.x * 4;
    if (base + 0 < N) h1out[(size_t)(base + 0) * 256 + t] = fmaxf(o0 + bb, 0.f);
    if (base + 1 < N) h1out[(size_t)(base + 1) * 256 + t] = fmaxf(o1 + bb, 0.f);
    if (base + 2 < N) h1out[(size_t)(base + 2) * 256 + t] = fmaxf(o2 + bb, 0.f);
    if (base + 3 < N) h1out[(size_t)(base + 3) * 256 + t] = fmaxf(o3 + bb, 0.f);
}

// --------- GAT layer 2 (1 head): wave per dst, inline weights + classifier ---
__global__ void k_gat2(const float* __restrict__ hlin, const float* __restrict__ as2,
                       const float* __restrict__ ad2, const int* __restrict__ rowptr,
                       const int* __restrict__ csrc, const float* __restrict__ bias,
                       const float* __restrict__ clsW, const float* __restrict__ clsB,
                       float* __restrict__ out, int N) {
    int t = threadIdx.x, wv = t >> 6, lane = t & 63;
    int slot = lane >> 4, sl = lane & 15;
    int d = blockIdx.x * 4 + wv;
    if (d >= N) return;
    int s0 = rowptr[d], e0 = rowptr[d + 1];
    float add = ad2[d];
    float ax = 0.f, ay = 0.f, az = 0.f, aw = 0.f, den = 0.f;
    const float* hb = hlin + sl * 4;
    if (slot == 0) {   // self-loop
        float z = as2[d] + add;
        z = (z > 0.f) ? z : NEG_SLOPE * z;
        float w = __expf(z);
        float4 hv = *(const float4*)(hb + (size_t)d * 64);
        ax = w * hv.x; ay = w * hv.y; az = w * hv.z; aw = w * hv.w;
        den = w;
    }
    for (int j = s0 + slot; j < e0; j += 4) {
        int s = csrc[j];
        float z = as2[s] + add;
        z = (z > 0.f) ? z : NEG_SLOPE * z;
        float w = __expf(z);
        float4 hv = *(const float4*)(hb + (size_t)s * 64);
        ax = fmaf(w, hv.x, ax); ay = fmaf(w, hv.y, ay);
        az = fmaf(w, hv.z, az); aw = fmaf(w, hv.w, aw);
        den += w;
    }
#pragma unroll
    for (int off = 16; off <= 32; off <<= 1) {
        ax += __shfl_xor(ax, off, 64); ay += __shfl_xor(ay, off, 64);
        az += __shfl_xor(az, off, 64); aw += __shfl_xor(aw, off, 64);
        den += __shfl_xor(den, off, 64);
    }
    float inv = 1.f / den;
    float4 bb = *(const float4*)(bias + sl * 4);
    float4 cw = *(const float4*)(clsW + sl * 4);
    float p = fmaxf(fmaf(ax, inv, bb.x), 0.f) * cw.x
            + fmaxf(fmaf(ay, inv, bb.y), 0.f) * cw.y
            + fmaxf(fmaf(az, inv, bb.z), 0.f) * cw.z
            + fmaxf(fmaf(aw, inv, bb.w), 0.f) * cw.w;
#pragma unroll
    for (int off = 1; off <= 8; off <<= 1) p += __shfl_xor(p, off, 64);
    if (lane == 0) out[d] = p + clsB[0];
}

extern "C" void kernel_launch(void* const* d_in, const int* in_sizes, int n_in,
                              void* d_out, int out_size, void* d_ws, size_t ws_size,
                              hipStream_t stream) {
    const float* x     = (const float*)d_in[0];
    const int*   ei    = (const int*)d_in[1];
    const float* projW = (const float*)d_in[2];
    const float* projB = (const float*)d_in[3];
    const float* W1    = (const float*)d_in[4];
    const float* as1w  = (const float*)d_in[5];
    const float* ad1w  = (const float*)d_in[6];
    const float* b1    = (const float*)d_in[7];
    const float* W2    = (const float*)d_in[8];
    const float* as2w  = (const float*)d_in[9];
    const float* ad2w  = (const float*)d_in[10];
    const float* b2    = (const float*)d_in[11];
    const float* clsW  = (const float*)d_in[12];
    const float* clsB  = (const float*)d_in[13];
    float* out = (float*)d_out;

    const int N = in_sizes[0] / F_IN;
    const int E = in_sizes[1] / 2;

    char* ws = (char*)d_ws;
    size_t off = 0;
    auto alloc = [&](size_t bytes) -> void* {
        void* p = ws + off;
        off += (bytes + 255) & ~(size_t)255;
        return p;
    };
    float* h0     = (float*)alloc((size_t)N * 64 * 4);   // reused as h2lin
    float* h1     = (float*)alloc((size_t)N * 256 * 4);
    float* as1    = (float*)alloc((size_t)N * 4 * 4);
    float* ad1    = (float*)alloc((size_t)N * 4 * 4);
    float* as2    = (float*)alloc((size_t)N * 4);
    float* ad2    = (float*)alloc((size_t)N * 4);
    int*   dc     = (int*)alloc((size_t)2 * N * 4);      // deg | cursor adjacent
    int*   deg    = dc;
    int*   cursor = dc + N;
    int*   rowptr = (int*)alloc((size_t)(N + 1) * 4);
    int*   parts  = (int*)alloc(1024 * 4);
    int*   csrc   = (int*)alloc((size_t)E * 4);
    float* wt0    = (float*)alloc(64 * KP_PROJ * 4);
    float* wt2    = (float*)alloc(64 * 256 * 4);
    float* va     = (float*)alloc(512 * 4);
    float* h2lin  = h0;

    // weight transposes + va vectors
    k_trans<<<(64 * KP_PROJ + 64 * 256 + 512 + 255) / 256, 256, 0, stream>>>(
        projW, W2, W1, as1w, ad1w, wt0, wt2, va);

    // CSR build (real edges only; self-loops inline in aggregation kernels)
    hipMemsetAsync(dc, 0, (size_t)2 * N * 4, stream);
    k_deg<<<1024, 256, 0, stream>>>(ei, E, deg);
    int nblk = (N + 1023) / 1024;
    k_scan_part<<<nblk, 1024, 0, stream>>>(deg, rowptr, parts, N);
    k_scan_small<<<1, 64, 0, stream>>>(parts, nblk);
    k_scan_add<<<nblk, 1024, 0, stream>>>(rowptr, parts, N, E);
    k_scatter<<<1024, 256, 0, stream>>>(ei, E, rowptr, cursor, csrc);

    // MLP in (+ fused as1/ad1 reduction)
    k_proj<<<(N + 31) / 32, 256, 0, stream>>>(x, wt0, projB, va, h0, as1, ad1, N);

    // GAT layer 1 (h0-domain aggregation, edge weights inline)
    k_gat1f<<<(N + 3) / 4, 256, 0, stream>>>(h0, as1, ad1, rowptr, csrc, W1, b1, h1, N);

    // GAT layer 2 + classifier (edge weights fused into k_gat2)
    k_lin2<<<(N + 31) / 32, 256, 0, stream>>>(h1, wt2, as2w, ad2w, h2lin, as2, ad2, N);
    k_gat2<<<(N + 3) / 4, 256, 0, stream>>>(h2lin, as2, ad2, rowptr, csrc, b2,
                                            clsW, clsB, out, N);
}

// Round 15
// 314.767 us; speedup vs baseline: 1.1051x; 1.0675x over previous
//
#include <hip/hip_runtime.h>

#define F_IN 165
#define KP_PROJ 168
constexpr float NEG_SLOPE = 0.2f;

// ---- weight transposes + va vectors (va[i][k], i = plane*4+head) -----------
__global__ void k_trans(const float* __restrict__ pw, const float* __restrict__ w2,
                        const float* __restrict__ w1, const float* __restrict__ as1w,
                        const float* __restrict__ ad1w,
                        float* __restrict__ t0, float* __restrict__ t2,
                        float* __restrict__ va) {
    int i = blockIdx.x * 256 + threadIdx.x;
    const int n0 = 64 * KP_PROJ, n2 = 64 * 256;
    if (i < n0) {
        int c = i / KP_PROJ, r = i - c * KP_PROJ;
        t0[i] = (r < F_IN) ? pw[r * 64 + c] : 0.f;
    } else if (i < n0 + n2) {
        int j = i - n0; int c = j >> 8, r = j & 255;
        t2[j] = w2[r * 64 + c];
    } else if (i < n0 + n2 + 512) {
        int j = i - n0 - n2;          // 0..511
        int i2 = j >> 6;              // 0..7 = plane*4 + h
        int plane = i2 >> 2, h = i2 & 3, k = j & 63;
        const float* att = plane ? ad1w : as1w;
        float acc = 0.f;
        for (int c = 0; c < 64; ++c)
            acc = fmaf(w1[k * 256 + h * 64 + c], att[h * 64 + c], acc);
        va[j] = acc;
    }
}

// ---- h0 = relu(x @ W + b) + fused as1/ad1 via single-wave LDS transpose -----
// att reduction: instead of 8 full 64-lane butterflies per node (~104 inst),
// stage the h-row in wave-private LDS, lane (i8=lane&7, c8=lane>>3) computes
// va-vector i8 over col chunk c8 (8 FMAs) then 3 shfl_xor steps (~31 inst).
// vas padded [8][65] to avoid the stride-64 8-way bank conflict.
__global__ void k_proj(const float* __restrict__ x, const float* __restrict__ Wt,
                       const float* __restrict__ b, const float* __restrict__ va,
                       float* __restrict__ h0, float* __restrict__ as_,
                       float* __restrict__ ad_, int N) {
    __shared__ float xs[32][KP_PROJ];
    __shared__ float vas[8][65];
    __shared__ float hrow[4][64];
    int base = blockIdx.x * 32;
    int t = threadIdx.x;
    for (int idx = t; idx < 512; idx += 256)
        vas[idx >> 6][idx & 63] = va[idx];
    for (int idx = t; idx < 32 * KP_PROJ; idx += 256) {
        int nl = idx / KP_PROJ, k = idx - nl * KP_PROJ;
        int node = base + nl;
        xs[nl][k] = (node < N && k < F_IN) ? x[(size_t)node * F_IN + k] : 0.f;
    }
    __syncthreads();
    int g = t >> 6, col = t & 63;
    float acc[8];
    float bb = b[col];
#pragma unroll
    for (int m = 0; m < 8; ++m) acc[m] = bb;
    const float* wrow = Wt + col * KP_PROJ;
    for (int k4 = 0; k4 < KP_PROJ / 4; ++k4) {
        float4 wv = *(const float4*)(wrow + k4 * 4);
#pragma unroll
        for (int m = 0; m < 8; ++m) {
            float4 av = *(const float4*)&xs[g * 8 + m][k4 * 4];
            acc[m] = fmaf(av.x, wv.x, acc[m]);
            acc[m] = fmaf(av.y, wv.y, acc[m]);
            acc[m] = fmaf(av.z, wv.z, acc[m]);
            acc[m] = fmaf(av.w, wv.w, acc[m]);
        }
    }
    int i8 = col & 7, c8 = col >> 3;
    const float* vbase = &vas[i8][c8 * 8];
    const float* hbase = &hrow[g][c8 * 8];
#pragma unroll
    for (int m = 0; m < 8; ++m) {
        int node = base + g * 8 + m;
        float h = fmaxf(acc[m], 0.f);
        if (node < N) h0[(size_t)node * 64 + col] = h;
        hrow[g][col] = h;            // wave-private LDS, wave-synchronous use
        float r = 0.f;
#pragma unroll
        for (int e = 0; e < 8; ++e)
            r = fmaf(hbase[e], vbase[e], r);
        r += __shfl_xor(r, 8, 64);
        r += __shfl_xor(r, 16, 64);
        r += __shfl_xor(r, 32, 64);
        if (node < N && col < 8) {
            if (col < 4) as_[(size_t)node * 4 + col] = r;
            else         ad_[(size_t)node * 4 + (col - 4)] = r;
        }
    }
}

// ---- h2lin = h1 @ W2: Wt2[64][256], 32 nodes/block, 4 groups x 8, fused att -
__global__ void k_lin2(const float* __restrict__ h1, const float* __restrict__ Wt,
                       const float* __restrict__ att_s, const float* __restrict__ att_d,
                       float* __restrict__ out, float* __restrict__ as_,
                       float* __restrict__ ad_, int N) {
    __shared__ float hs[32][256];
    int base = blockIdx.x * 32;
    int t = threadIdx.x;
    for (int i = 0; i < 8; ++i) {
        int idx4 = t + i * 256;
        int nl = idx4 >> 6, k4 = idx4 & 63;
        int node = base + nl;
        float4 v = make_float4(0.f, 0.f, 0.f, 0.f);
        if (node < N) v = *(const float4*)(h1 + (size_t)node * 256 + k4 * 4);
        *(float4*)&hs[nl][k4 * 4] = v;
    }
    __syncthreads();
    int g = t >> 6, col = t & 63;
    float acc[8] = {};
    const float* wrow = Wt + col * 256;
    for (int k4 = 0; k4 < 64; ++k4) {
        float4 wv = *(const float4*)(wrow + k4 * 4);
#pragma unroll
        for (int m = 0; m < 8; ++m) {
            float4 av = *(const float4*)&hs[g * 8 + m][k4 * 4];
            acc[m] = fmaf(av.x, wv.x, acc[m]);
            acc[m] = fmaf(av.y, wv.y, acc[m]);
            acc[m] = fmaf(av.z, wv.z, acc[m]);
            acc[m] = fmaf(av.w, wv.w, acc[m]);
        }
    }
    float sw = att_s[col], dw = att_d[col];
#pragma unroll
    for (int m = 0; m < 8; ++m) {
        int node = base + g * 8 + m;
        if (node < N) out[(size_t)node * 64 + col] = acc[m];
        float sv = acc[m] * sw, dv = acc[m] * dw;
#pragma unroll
        for (int off = 32; off; off >>= 1) {
            sv += __shfl_xor(sv, off, 64);
            dv += __shfl_xor(dv, off, 64);
        }
        if (col == 0 && node < N) { as_[node] = sv; ad_[node] = dv; }
    }
}

// ------- CSR build over REAL edges only (self-loops handled inline) ----------
__global__ void k_deg(const int* __restrict__ ei, int E, int* __restrict__ deg) {
    for (int i = blockIdx.x * blockDim.x + threadIdx.x; i < E; i += gridDim.x * blockDim.x) {
        atomicAdd(&deg[ei[E + i]], 1);
    }
}

__global__ void k_scan_part(const int* __restrict__ deg, int* __restrict__ out,
                            int* __restrict__ partials, int n) {
    __shared__ int tmp[1024];
    int b = blockIdx.x, t = threadIdx.x;
    int i = b * 1024 + t;
    int v = (i < n) ? deg[i] : 0;
    tmp[t] = v;
    __syncthreads();
    for (int off = 1; off < 1024; off <<= 1) {
        int xval = (t >= off) ? tmp[t - off] : 0;
        __syncthreads();
        tmp[t] += xval;
        __syncthreads();
    }
    if (i < n) out[i] = tmp[t] - v; // exclusive
    if (t == 1023) partials[b] = tmp[t];
}

__global__ void k_scan_small(int* __restrict__ partials, int nblk) {
    int lane = threadIdx.x & 63;
    int carry = 0;
    for (int base = 0; base < nblk; base += 64) {
        int idx = base + lane;
        int v = (idx < nblk) ? partials[idx] : 0;
        int orig = v;
#pragma unroll
        for (int off = 1; off < 64; off <<= 1) {
            int u = __shfl_up(v, off, 64);
            if (lane >= off) v += u;
        }
        if (idx < nblk) partials[idx] = carry + v - orig; // exclusive
        carry += __shfl(v, 63, 64);
    }
}

__global__ void k_scan_add(int* __restrict__ rowptr, const int* __restrict__ partials,
                           int n, int total) {
    int i = blockIdx.x * 1024 + threadIdx.x;
    if (i < n) rowptr[i] += partials[blockIdx.x];
    if (i == 0) rowptr[n] = total;
}

__global__ void k_scatter(const int* __restrict__ ei, int E,
                          const int* __restrict__ rowptr, int* __restrict__ cursor,
                          int* __restrict__ csrc) {
    for (int i = blockIdx.x * blockDim.x + threadIdx.x; i < E; i += gridDim.x * blockDim.x) {
        int src = ei[i], dst = ei[E + i];
        int pos = rowptr[dst] + atomicAdd(&cursor[dst], 1);
        csrc[pos] = src;
    }
}

// --------- GAT layer 1 fused: inline edge weights + h0 agg + W1 GEMM ---------
// 8 dsts/block (512 thr, 8 waves): phase 1 identical per wave; phase 2 runs as
// two 256-thread halves, each the r10/r12-proven 4-node loop (scalar W1 +
// scalar LDS -- do NOT vectorize (spills r4/5/9), pin unroll 1 (r11), or
// transpose agg (r13 bank conflicts)). W1 L2 refetch halves vs 4-dst blocks.
__global__ void k_gat1f(const float* __restrict__ h0, const float* __restrict__ as1,
                        const float* __restrict__ ad1, const int* __restrict__ rowptr,
                        const int* __restrict__ csrc, const float* __restrict__ W1,
                        const float* __restrict__ b1, float* __restrict__ h1out, int N) {
    __shared__ float agg[8][256];
    int t = threadIdx.x, wv = t >> 6, lane = t & 63;
    int slot = lane >> 4, sl = lane & 15;
    int d = blockIdx.x * 8 + wv;
    if (d < N) {
        int s0 = rowptr[d], e0 = rowptr[d + 1];
        float4 ad = *(const float4*)(ad1 + (size_t)d * 4);
        float a00=0,a01=0,a02=0,a03=0;
        float a10=0,a11=0,a12=0,a13=0;
        float a20=0,a21=0,a22=0,a23=0;
        float a30=0,a31=0,a32=0,a33=0;
        float d0=0,d1=0,d2=0,d3=0;
        const float* hb = h0 + sl * 4;
        if (slot == 0) {
            // self-loop
            float4 a = *(const float4*)(as1 + (size_t)d * 4);
            float z0 = a.x + ad.x, z1 = a.y + ad.y, z2 = a.z + ad.z, z3 = a.w + ad.w;
            z0 = (z0 > 0.f) ? z0 : NEG_SLOPE * z0;
            z1 = (z1 > 0.f) ? z1 : NEG_SLOPE * z1;
            z2 = (z2 > 0.f) ? z2 : NEG_SLOPE * z2;
            z3 = (z3 > 0.f) ? z3 : NEG_SLOPE * z3;
            float wx = __expf(z0), wy = __expf(z1), wz = __expf(z2), ww = __expf(z3);
            float4 hv = *(const float4*)(hb + (size_t)d * 64);
            a00 = wx*hv.x; a01 = wx*hv.y; a02 = wx*hv.z; a03 = wx*hv.w;
            a10 = wy*hv.x; a11 = wy*hv.y; a12 = wy*hv.z; a13 = wy*hv.w;
            a20 = wz*hv.x; a21 = wz*hv.y; a22 = wz*hv.z; a23 = wz*hv.w;
            a30 = ww*hv.x; a31 = ww*hv.y; a32 = ww*hv.z; a33 = ww*hv.w;
            d0 = wx; d1 = wy; d2 = wz; d3 = ww;
        }
        for (int j = s0 + slot; j < e0; j += 4) {
            int s = csrc[j];
            float4 a = *(const float4*)(as1 + (size_t)s * 4);
            float4 hv = *(const float4*)(hb + (size_t)s * 64);
            float z0 = a.x + ad.x, z1 = a.y + ad.y, z2 = a.z + ad.z, z3 = a.w + ad.w;
            z0 = (z0 > 0.f) ? z0 : NEG_SLOPE * z0;
            z1 = (z1 > 0.f) ? z1 : NEG_SLOPE * z1;
            z2 = (z2 > 0.f) ? z2 : NEG_SLOPE * z2;
            z3 = (z3 > 0.f) ? z3 : NEG_SLOPE * z3;
            float wx = __expf(z0), wy = __expf(z1), wz = __expf(z2), ww = __expf(z3);
            a00 = fmaf(wx, hv.x, a00); a01 = fmaf(wx, hv.y, a01);
            a02 = fmaf(wx, hv.z, a02); a03 = fmaf(wx, hv.w, a03);
            a10 = fmaf(wy, hv.x, a10); a11 = fmaf(wy, hv.y, a11);
            a12 = fmaf(wy, hv.z, a12); a13 = fmaf(wy, hv.w, a13);
            a20 = fmaf(wz, hv.x, a20); a21 = fmaf(wz, hv.y, a21);
            a22 = fmaf(wz, hv.z, a22); a23 = fmaf(wz, hv.w, a23);
            a30 = fmaf(ww, hv.x, a30); a31 = fmaf(ww, hv.y, a31);
            a32 = fmaf(ww, hv.z, a32); a33 = fmaf(ww, hv.w, a33);
            d0 += wx; d1 += wy; d2 += wz; d3 += ww;
        }
#pragma unroll
        for (int off = 16; off <= 32; off <<= 1) {
            a00 += __shfl_xor(a00, off, 64); a01 += __shfl_xor(a01, off, 64);
            a02 += __shfl_xor(a02, off, 64); a03 += __shfl_xor(a03, off, 64);
            a10 += __shfl_xor(a10, off, 64); a11 += __shfl_xor(a11, off, 64);
            a12 += __shfl_xor(a12, off, 64); a13 += __shfl_xor(a13, off, 64);
            a20 += __shfl_xor(a20, off, 64); a21 += __shfl_xor(a21, off, 64);
            a22 += __shfl_xor(a22, off, 64); a23 += __shfl_xor(a23, off, 64);
            a30 += __shfl_xor(a30, off, 64); a31 += __shfl_xor(a31, off, 64);
            a32 += __shfl_xor(a32, off, 64); a33 += __shfl_xor(a33, off, 64);
            d0  += __shfl_xor(d0,  off, 64); d1  += __shfl_xor(d1,  off, 64);
            d2  += __shfl_xor(d2,  off, 64); d3  += __shfl_xor(d3,  off, 64);
        }
        if (slot == 0) {
            float i0 = 1.f / d0, i1 = 1.f / d1, i2 = 1.f / d2, i3 = 1.f / d3;
            *(float4*)&agg[wv][  0 + sl * 4] = make_float4(a00*i0, a01*i0, a02*i0, a03*i0);
            *(float4*)&agg[wv][ 64 + sl * 4] = make_float4(a10*i1, a11*i1, a12*i1, a13*i1);
            *(float4*)&agg[wv][128 + sl * 4] = make_float4(a20*i2, a21*i2, a22*i2, a23*i2);
            *(float4*)&agg[wv][192 + sl * 4] = make_float4(a30*i3, a31*i3, a32*i3, a33*i3);
        }
    }
    __syncthreads();
    int half = t >> 8;          // 0: nodes 0-3, 1: nodes 4-7
    int tc = t & 255;           // output column
    int h = tc >> 6;
    const float (*ag)[256] = &agg[half * 4];
    float o0 = 0.f, o1 = 0.f, o2 = 0.f, o3 = 0.f;
    for (int k = 0; k < 64; ++k) {
        float wv1 = W1[k * 256 + tc];
        o0 = fmaf(ag[0][h * 64 + k], wv1, o0);
        o1 = fmaf(ag[1][h * 64 + k], wv1, o1);
        o2 = fmaf(ag[2][h * 64 + k], wv1, o2);
        o3 = fmaf(ag[3][h * 64 + k], wv1, o3);
    }
    float bb = b1[tc];
    int base = blockIdx.x * 8 + half * 4;
    if (base + 0 < N) h1out[(size_t)(base + 0) * 256 + tc] = fmaxf(o0 + bb, 0.f);
    if (base + 1 < N) h1out[(size_t)(base + 1) * 256 + tc] = fmaxf(o1 + bb, 0.f);
    if (base + 2 < N) h1out[(size_t)(base + 2) * 256 + tc] = fmaxf(o2 + bb, 0.f);
    if (base + 3 < N) h1out[(size_t)(base + 3) * 256 + tc] = fmaxf(o3 + bb, 0.f);
}

// --------- GAT layer 2 (1 head): wave per dst, inline weights + classifier ---
__global__ void k_gat2(const float* __restrict__ hlin, const float* __restrict__ as2,
                       const float* __restrict__ ad2, const int* __restrict__ rowptr,
                       const int* __restrict__ csrc, const float* __restrict__ bias,
                       const float* __restrict__ clsW, const float* __restrict__ clsB,
                       float* __restrict__ out, int N) {
    int t = threadIdx.x, wv = t >> 6, lane = t & 63;
    int slot = lane >> 4, sl = lane & 15;
    int d = blockIdx.x * 4 + wv;
    if (d >= N) return;
    int s0 = rowptr[d], e0 = rowptr[d + 1];
    float add = ad2[d];
    float ax = 0.f, ay = 0.f, az = 0.f, aw = 0.f, den = 0.f;
    const float* hb = hlin + sl * 4;
    if (slot == 0) {   // self-loop
        float z = as2[d] + add;
        z = (z > 0.f) ? z : NEG_SLOPE * z;
        float w = __expf(z);
        float4 hv = *(const float4*)(hb + (size_t)d * 64);
        ax = w * hv.x; ay = w * hv.y; az = w * hv.z; aw = w * hv.w;
        den = w;
    }
    for (int j = s0 + slot; j < e0; j += 4) {
        int s = csrc[j];
        float z = as2[s] + add;
        z = (z > 0.f) ? z : NEG_SLOPE * z;
        float w = __expf(z);
        float4 hv = *(const float4*)(hb + (size_t)s * 64);
        ax = fmaf(w, hv.x, ax); ay = fmaf(w, hv.y, ay);
        az = fmaf(w, hv.z, az); aw = fmaf(w, hv.w, aw);
        den += w;
    }
#pragma unroll
    for (int off = 16; off <= 32; off <<= 1) {
        ax += __shfl_xor(ax, off, 64); ay += __shfl_xor(ay, off, 64);
        az += __shfl_xor(az, off, 64); aw += __shfl_xor(aw, off, 64);
        den += __shfl_xor(den, off, 64);
    }
    float inv = 1.f / den;
    float4 bb = *(const float4*)(bias + sl * 4);
    float4 cw = *(const float4*)(clsW + sl * 4);
    float p = fmaxf(fmaf(ax, inv, bb.x), 0.f) * cw.x
            + fmaxf(fmaf(ay, inv, bb.y), 0.f) * cw.y
            + fmaxf(fmaf(az, inv, bb.z), 0.f) * cw.z
            + fmaxf(fmaf(aw, inv, bb.w), 0.f) * cw.w;
#pragma unroll
    for (int off = 1; off <= 8; off <<= 1) p += __shfl_xor(p, off, 64);
    if (lane == 0) out[d] = p + clsB[0];
}

extern "C" void kernel_launch(void* const* d_in, const int* in_sizes, int n_in,
                              void* d_out, int out_size, void* d_ws, size_t ws_size,
                              hipStream_t stream) {
    const float* x     = (const float*)d_in[0];
    const int*   ei    = (const int*)d_in[1];
    const float* projW = (const float*)d_in[2];
    const float* projB = (const float*)d_in[3];
    const float* W1    = (const float*)d_in[4];
    const float* as1w  = (const float*)d_in[5];
    const float* ad1w  = (const float*)d_in[6];
    const float* b1    = (const float*)d_in[7];
    const float* W2    = (const float*)d_in[8];
    const float* as2w  = (const float*)d_in[9];
    const float* ad2w  = (const float*)d_in[10];
    const float* b2    = (const float*)d_in[11];
    const float* clsW  = (const float*)d_in[12];
    const float* clsB  = (const float*)d_in[13];
    float* out = (float*)d_out;

    const int N = in_sizes[0] / F_IN;
    const int E = in_sizes[1] / 2;

    char* ws = (char*)d_ws;
    size_t off = 0;
    auto alloc = [&](size_t bytes) -> void* {
        void* p = ws + off;
        off += (bytes + 255) & ~(size_t)255;
        return p;
    };
    float* h0     = (float*)alloc((size_t)N * 64 * 4);   // reused as h2lin
    float* h1     = (float*)alloc((size_t)N * 256 * 4);
    float* as1    = (float*)alloc((size_t)N * 4 * 4);
    float* ad1    = (float*)alloc((size_t)N * 4 * 4);
    float* as2    = (float*)alloc((size_t)N * 4);
    float* ad2    = (float*)alloc((size_t)N * 4);
    int*   dc     = (int*)alloc((size_t)2 * N * 4);      // deg | cursor adjacent
    int*   deg    = dc;
    int*   cursor = dc + N;
    int*   rowptr = (int*)alloc((size_t)(N + 1) * 4);
    int*   parts  = (int*)alloc(1024 * 4);
    int*   csrc   = (int*)alloc((size_t)E * 4);
    float* wt0    = (float*)alloc(64 * KP_PROJ * 4);
    float* wt2    = (float*)alloc(64 * 256 * 4);
    float* va     = (float*)alloc(512 * 4);
    float* h2lin  = h0;

    // weight transposes + va vectors
    k_trans<<<(64 * KP_PROJ + 64 * 256 + 512 + 255) / 256, 256, 0, stream>>>(
        projW, W2, W1, as1w, ad1w, wt0, wt2, va);

    // CSR build (real edges only; self-loops inline in aggregation kernels)
    hipMemsetAsync(dc, 0, (size_t)2 * N * 4, stream);
    k_deg<<<1024, 256, 0, stream>>>(ei, E, deg);
    int nblk = (N + 1023) / 1024;
    k_scan_part<<<nblk, 1024, 0, stream>>>(deg, rowptr, parts, N);
    k_scan_small<<<1, 64, 0, stream>>>(parts, nblk);
    k_scan_add<<<nblk, 1024, 0, stream>>>(rowptr, parts, N, E);
    k_scatter<<<1024, 256, 0, stream>>>(ei, E, rowptr, cursor, csrc);

    // MLP in (+ fused as1/ad1 reduction)
    k_proj<<<(N + 31) / 32, 256, 0, stream>>>(x, wt0, projB, va, h0, as1, ad1, N);

    // GAT layer 1 (h0-domain aggregation, edge weights inline, 8 dst/block)
    k_gat1f<<<(N + 7) / 8, 512, 0, stream>>>(h0, as1, ad1, rowptr, csrc, W1, b1, h1, N);

    // GAT layer 2 + classifier (edge weights fused into k_gat2)
    k_lin2<<<(N + 31) / 32, 256, 0, stream>>>(h1, wt2, as2w, ad2w, h2lin, as2, ad2, N);
    k_gat2<<<(N + 3) / 4, 256, 0, stream>>>(h2lin, as2, ad2, rowptr, csrc, b2,
                                            clsW, clsB, out, N);
}

// Round 16
// 311.441 us; speedup vs baseline: 1.1169x; 1.0107x over previous
//
#include <hip/hip_runtime.h>

#define F_IN 165
#define KP_PROJ 168
constexpr float NEG_SLOPE = 0.2f;

// lrelu(z) = max(z, 0.2z) -- 2 VALU inst vs 3 for cmp/cndmask form.
__device__ __forceinline__ float lrelu(float z) { return fmaxf(z, NEG_SLOPE * z); }

// ---- weight transposes + va vectors + workspace zeroing ---------------------
// Extra trailing blocks zero the deg|cursor array (saves a memset dispatch).
__global__ void k_trans(const float* __restrict__ pw, const float* __restrict__ w2,
                        const float* __restrict__ w1, const float* __restrict__ as1w,
                        const float* __restrict__ ad1w,
                        float* __restrict__ t0, float* __restrict__ t2,
                        float* __restrict__ va, int* __restrict__ dc, int ndc) {
    int i = blockIdx.x * 256 + threadIdx.x;
    const int n0 = 64 * KP_PROJ, n2 = 64 * 256;
    if (i < n0) {
        int c = i / KP_PROJ, r = i - c * KP_PROJ;
        t0[i] = (r < F_IN) ? pw[r * 64 + c] : 0.f;
    } else if (i < n0 + n2) {
        int j = i - n0; int c = j >> 8, r = j & 255;
        t2[j] = w2[r * 64 + c];
    } else if (i < n0 + n2 + 512) {
        int j = i - n0 - n2;          // 0..511
        int i2 = j >> 6;              // 0..7 = plane*4 + h
        int plane = i2 >> 2, h = i2 & 3, k = j & 63;
        const float* att = plane ? ad1w : as1w;
        float acc = 0.f;
        for (int c = 0; c < 64; ++c)
            acc = fmaf(w1[k * 256 + h * 64 + c], att[h * 64 + c], acc);
        va[j] = acc;
    }
    int z = i - (n0 + n2 + 512);
    if (z >= 0 && z < ndc) dc[z] = 0;
}

// ---- h0 = relu(x @ W + b) + fused as1/ad1 via single-wave LDS transpose -----
__global__ void k_proj(const float* __restrict__ x, const float* __restrict__ Wt,
                       const float* __restrict__ b, const float* __restrict__ va,
                       float* __restrict__ h0, float* __restrict__ as_,
                       float* __restrict__ ad_, int N) {
    __shared__ float xs[32][KP_PROJ];
    __shared__ float vas[8][65];
    __shared__ float hrow[4][64];
    int base = blockIdx.x * 32;
    int t = threadIdx.x;
    for (int idx = t; idx < 512; idx += 256)
        vas[idx >> 6][idx & 63] = va[idx];
    for (int idx = t; idx < 32 * KP_PROJ; idx += 256) {
        int nl = idx / KP_PROJ, k = idx - nl * KP_PROJ;
        int node = base + nl;
        xs[nl][k] = (node < N && k < F_IN) ? x[(size_t)node * F_IN + k] : 0.f;
    }
    __syncthreads();
    int g = t >> 6, col = t & 63;
    float acc[8];
    float bb = b[col];
#pragma unroll
    for (int m = 0; m < 8; ++m) acc[m] = bb;
    const float* wrow = Wt + col * KP_PROJ;
    for (int k4 = 0; k4 < KP_PROJ / 4; ++k4) {
        float4 wv = *(const float4*)(wrow + k4 * 4);
#pragma unroll
        for (int m = 0; m < 8; ++m) {
            float4 av = *(const float4*)&xs[g * 8 + m][k4 * 4];
            acc[m] = fmaf(av.x, wv.x, acc[m]);
            acc[m] = fmaf(av.y, wv.y, acc[m]);
            acc[m] = fmaf(av.z, wv.z, acc[m]);
            acc[m] = fmaf(av.w, wv.w, acc[m]);
        }
    }
    int i8 = col & 7, c8 = col >> 3;
    const float* vbase = &vas[i8][c8 * 8];
    const float* hbase = &hrow[g][c8 * 8];
#pragma unroll
    for (int m = 0; m < 8; ++m) {
        int node = base + g * 8 + m;
        float h = fmaxf(acc[m], 0.f);
        if (node < N) h0[(size_t)node * 64 + col] = h;
        hrow[g][col] = h;            // wave-private LDS, wave-synchronous use
        float r = 0.f;
#pragma unroll
        for (int e = 0; e < 8; ++e)
            r = fmaf(hbase[e], vbase[e], r);
        r += __shfl_xor(r, 8, 64);
        r += __shfl_xor(r, 16, 64);
        r += __shfl_xor(r, 32, 64);
        if (node < N && col < 8) {
            if (col < 4) as_[(size_t)node * 4 + col] = r;
            else         ad_[(size_t)node * 4 + (col - 4)] = r;
        }
    }
}

// ---- h2lin = h1 @ W2: Wt2[64][256], 32 nodes/block, 4 groups x 8, fused att -
__global__ void k_lin2(const float* __restrict__ h1, const float* __restrict__ Wt,
                       const float* __restrict__ att_s, const float* __restrict__ att_d,
                       float* __restrict__ out, float* __restrict__ as_,
                       float* __restrict__ ad_, int N) {
    __shared__ float hs[32][256];
    int base = blockIdx.x * 32;
    int t = threadIdx.x;
    for (int i = 0; i < 8; ++i) {
        int idx4 = t + i * 256;
        int nl = idx4 >> 6, k4 = idx4 & 63;
        int node = base + nl;
        float4 v = make_float4(0.f, 0.f, 0.f, 0.f);
        if (node < N) v = *(const float4*)(h1 + (size_t)node * 256 + k4 * 4);
        *(float4*)&hs[nl][k4 * 4] = v;
    }
    __syncthreads();
    int g = t >> 6, col = t & 63;
    float acc[8] = {};
    const float* wrow = Wt + col * 256;
    for (int k4 = 0; k4 < 64; ++k4) {
        float4 wv = *(const float4*)(wrow + k4 * 4);
#pragma unroll
        for (int m = 0; m < 8; ++m) {
            float4 av = *(const float4*)&hs[g * 8 + m][k4 * 4];
            acc[m] = fmaf(av.x, wv.x, acc[m]);
            acc[m] = fmaf(av.y, wv.y, acc[m]);
            acc[m] = fmaf(av.z, wv.z, acc[m]);
            acc[m] = fmaf(av.w, wv.w, acc[m]);
        }
    }
    float sw = att_s[col], dw = att_d[col];
#pragma unroll
    for (int m = 0; m < 8; ++m) {
        int node = base + g * 8 + m;
        if (node < N) out[(size_t)node * 64 + col] = acc[m];
        float sv = acc[m] * sw, dv = acc[m] * dw;
#pragma unroll
        for (int off = 32; off; off >>= 1) {
            sv += __shfl_xor(sv, off, 64);
            dv += __shfl_xor(dv, off, 64);
        }
        if (col == 0 && node < N) { as_[node] = sv; ad_[node] = dv; }
    }
}

// ------- CSR build over REAL edges only (self-loops handled inline) ----------
__global__ void k_deg(const int* __restrict__ ei, int E, int* __restrict__ deg) {
    for (int i = blockIdx.x * blockDim.x + threadIdx.x; i < E; i += gridDim.x * blockDim.x) {
        atomicAdd(&deg[ei[E + i]], 1);
    }
}

__global__ void k_scan_part(const int* __restrict__ deg, int* __restrict__ out,
                            int* __restrict__ partials, int n) {
    __shared__ int tmp[1024];
    int b = blockIdx.x, t = threadIdx.x;
    int i = b * 1024 + t;
    int v = (i < n) ? deg[i] : 0;
    tmp[t] = v;
    __syncthreads();
    for (int off = 1; off < 1024; off <<= 1) {
        int xval = (t >= off) ? tmp[t - off] : 0;
        __syncthreads();
        tmp[t] += xval;
        __syncthreads();
    }
    if (i < n) out[i] = tmp[t] - v; // exclusive
    if (t == 1023) partials[b] = tmp[t];
}

__global__ void k_scan_small(int* __restrict__ partials, int nblk) {
    int lane = threadIdx.x & 63;
    int carry = 0;
    for (int base = 0; base < nblk; base += 64) {
        int idx = base + lane;
        int v = (idx < nblk) ? partials[idx] : 0;
        int orig = v;
#pragma unroll
        for (int off = 1; off < 64; off <<= 1) {
            int u = __shfl_up(v, off, 64);
            if (lane >= off) v += u;
        }
        if (idx < nblk) partials[idx] = carry + v - orig; // exclusive
        carry += __shfl(v, 63, 64);
    }
}

__global__ void k_scan_add(int* __restrict__ rowptr, const int* __restrict__ partials,
                           int n, int total) {
    int i = blockIdx.x * 1024 + threadIdx.x;
    if (i < n) rowptr[i] += partials[blockIdx.x];
    if (i == 0) rowptr[n] = total;
}

__global__ void k_scatter(const int* __restrict__ ei, int E,
                          const int* __restrict__ rowptr, int* __restrict__ cursor,
                          int* __restrict__ csrc) {
    for (int i = blockIdx.x * blockDim.x + threadIdx.x; i < E; i += gridDim.x * blockDim.x) {
        int src = ei[i], dst = ei[E + i];
        int pos = rowptr[dst] + atomicAdd(&cursor[dst], 1);
        csrc[pos] = src;
    }
}

// --------- GAT layer 1 fused: inline edge weights + h0 agg + W1 GEMM ---------
// 8 dsts/block (512 thr). Phase 2: scalar W1 + scalar LDS (r10/r12 proven).
// Do NOT vectorize (spills r4/5/9), pin unroll 1 (r11), or transpose (r13).
__global__ void k_gat1f(const float* __restrict__ h0, const float* __restrict__ as1,
                        const float* __restrict__ ad1, const int* __restrict__ rowptr,
                        const int* __restrict__ csrc, const float* __restrict__ W1,
                        const float* __restrict__ b1, float* __restrict__ h1out, int N) {
    __shared__ float agg[8][256];
    int t = threadIdx.x, wv = t >> 6, lane = t & 63;
    int slot = lane >> 4, sl = lane & 15;
    int d = blockIdx.x * 8 + wv;
    if (d < N) {
        int s0 = rowptr[d], e0 = rowptr[d + 1];
        float4 ad = *(const float4*)(ad1 + (size_t)d * 4);
        float a00=0,a01=0,a02=0,a03=0;
        float a10=0,a11=0,a12=0,a13=0;
        float a20=0,a21=0,a22=0,a23=0;
        float a30=0,a31=0,a32=0,a33=0;
        float d0=0,d1=0,d2=0,d3=0;
        const float* hb = h0 + sl * 4;
        if (slot == 0) {
            // self-loop
            float4 a = *(const float4*)(as1 + (size_t)d * 4);
            float wx = __expf(lrelu(a.x + ad.x));
            float wy = __expf(lrelu(a.y + ad.y));
            float wz = __expf(lrelu(a.z + ad.z));
            float ww = __expf(lrelu(a.w + ad.w));
            float4 hv = *(const float4*)(hb + (size_t)d * 64);
            a00 = wx*hv.x; a01 = wx*hv.y; a02 = wx*hv.z; a03 = wx*hv.w;
            a10 = wy*hv.x; a11 = wy*hv.y; a12 = wy*hv.z; a13 = wy*hv.w;
            a20 = wz*hv.x; a21 = wz*hv.y; a22 = wz*hv.z; a23 = wz*hv.w;
            a30 = ww*hv.x; a31 = ww*hv.y; a32 = ww*hv.z; a33 = ww*hv.w;
            d0 = wx; d1 = wy; d2 = wz; d3 = ww;
        }
        for (int j = s0 + slot; j < e0; j += 4) {
            int s = csrc[j];
            float4 a = *(const float4*)(as1 + (size_t)s * 4);
            float4 hv = *(const float4*)(hb + (size_t)s * 64);
            float wx = __expf(lrelu(a.x + ad.x));
            float wy = __expf(lrelu(a.y + ad.y));
            float wz = __expf(lrelu(a.z + ad.z));
            float ww = __expf(lrelu(a.w + ad.w));
            a00 = fmaf(wx, hv.x, a00); a01 = fmaf(wx, hv.y, a01);
            a02 = fmaf(wx, hv.z, a02); a03 = fmaf(wx, hv.w, a03);
            a10 = fmaf(wy, hv.x, a10); a11 = fmaf(wy, hv.y, a11);
            a12 = fmaf(wy, hv.z, a12); a13 = fmaf(wy, hv.w, a13);
            a20 = fmaf(wz, hv.x, a20); a21 = fmaf(wz, hv.y, a21);
            a22 = fmaf(wz, hv.z, a22); a23 = fmaf(wz, hv.w, a23);
            a30 = fmaf(ww, hv.x, a30); a31 = fmaf(ww, hv.y, a31);
            a32 = fmaf(ww, hv.z, a32); a33 = fmaf(ww, hv.w, a33);
            d0 += wx; d1 += wy; d2 += wz; d3 += ww;
        }
#pragma unroll
        for (int off = 16; off <= 32; off <<= 1) {
            a00 += __shfl_xor(a00, off, 64); a01 += __shfl_xor(a01, off, 64);
            a02 += __shfl_xor(a02, off, 64); a03 += __shfl_xor(a03, off, 64);
            a10 += __shfl_xor(a10, off, 64); a11 += __shfl_xor(a11, off, 64);
            a12 += __shfl_xor(a12, off, 64); a13 += __shfl_xor(a13, off, 64);
            a20 += __shfl_xor(a20, off, 64); a21 += __shfl_xor(a21, off, 64);
            a22 += __shfl_xor(a22, off, 64); a23 += __shfl_xor(a23, off, 64);
            a30 += __shfl_xor(a30, off, 64); a31 += __shfl_xor(a31, off, 64);
            a32 += __shfl_xor(a32, off, 64); a33 += __shfl_xor(a33, off, 64);
            d0  += __shfl_xor(d0,  off, 64); d1  += __shfl_xor(d1,  off, 64);
            d2  += __shfl_xor(d2,  off, 64); d3  += __shfl_xor(d3,  off, 64);
        }
        if (slot == 0) {
            float i0 = 1.f / d0, i1 = 1.f / d1, i2 = 1.f / d2, i3 = 1.f / d3;
            *(float4*)&agg[wv][  0 + sl * 4] = make_float4(a00*i0, a01*i0, a02*i0, a03*i0);
            *(float4*)&agg[wv][ 64 + sl * 4] = make_float4(a10*i1, a11*i1, a12*i1, a13*i1);
            *(float4*)&agg[wv][128 + sl * 4] = make_float4(a20*i2, a21*i2, a22*i2, a23*i2);
            *(float4*)&agg[wv][192 + sl * 4] = make_float4(a30*i3, a31*i3, a32*i3, a33*i3);
        }
    }
    __syncthreads();
    int half = t >> 8;          // 0: nodes 0-3, 1: nodes 4-7
    int tc = t & 255;           // output column
    int h = tc >> 6;
    const float (*ag)[256] = &agg[half * 4];
    float o0 = 0.f, o1 = 0.f, o2 = 0.f, o3 = 0.f;
    for (int k = 0; k < 64; ++k) {
        float wv1 = W1[k * 256 + tc];
        o0 = fmaf(ag[0][h * 64 + k], wv1, o0);
        o1 = fmaf(ag[1][h * 64 + k], wv1, o1);
        o2 = fmaf(ag[2][h * 64 + k], wv1, o2);
        o3 = fmaf(ag[3][h * 64 + k], wv1, o3);
    }
    float bb = b1[tc];
    int base = blockIdx.x * 8 + half * 4;
    if (base + 0 < N) h1out[(size_t)(base + 0) * 256 + tc] = fmaxf(o0 + bb, 0.f);
    if (base + 1 < N) h1out[(size_t)(base + 1) * 256 + tc] = fmaxf(o1 + bb, 0.f);
    if (base + 2 < N) h1out[(size_t)(base + 2) * 256 + tc] = fmaxf(o2 + bb, 0.f);
    if (base + 3 < N) h1out[(size_t)(base + 3) * 256 + tc] = fmaxf(o3 + bb, 0.f);
}

// --------- GAT layer 2 (1 head): wave per dst, inline weights + classifier ---
__global__ void k_gat2(const float* __restrict__ hlin, const float* __restrict__ as2,
                       const float* __restrict__ ad2, const int* __restrict__ rowptr,
                       const int* __restrict__ csrc, const float* __restrict__ bias,
                       const float* __restrict__ clsW, const float* __restrict__ clsB,
                       float* __restrict__ out, int N) {
    int t = threadIdx.x, wv = t >> 6, lane = t & 63;
    int slot = lane >> 4, sl = lane & 15;
    int d = blockIdx.x * 4 + wv;
    if (d >= N) return;
    int s0 = rowptr[d], e0 = rowptr[d + 1];
    float add = ad2[d];
    float ax = 0.f, ay = 0.f, az = 0.f, aw = 0.f, den = 0.f;
    const float* hb = hlin + sl * 4;
    if (slot == 0) {   // self-loop
        float w = __expf(lrelu(as2[d] + add));
        float4 hv = *(const float4*)(hb + (size_t)d * 64);
        ax = w * hv.x; ay = w * hv.y; az = w * hv.z; aw = w * hv.w;
        den = w;
    }
    for (int j = s0 + slot; j < e0; j += 4) {
        int s = csrc[j];
        float w = __expf(lrelu(as2[s] + add));
        float4 hv = *(const float4*)(hb + (size_t)s * 64);
        ax = fmaf(w, hv.x, ax); ay = fmaf(w, hv.y, ay);
        az = fmaf(w, hv.z, az); aw = fmaf(w, hv.w, aw);
        den += w;
    }
#pragma unroll
    for (int off = 16; off <= 32; off <<= 1) {
        ax += __shfl_xor(ax, off, 64); ay += __shfl_xor(ay, off, 64);
        az += __shfl_xor(az, off, 64); aw += __shfl_xor(aw, off, 64);
        den += __shfl_xor(den, off, 64);
    }
    float inv = 1.f / den;
    float4 bb = *(const float4*)(bias + sl * 4);
    float4 cw = *(const float4*)(clsW + sl * 4);
    float p = fmaxf(fmaf(ax, inv, bb.x), 0.f) * cw.x
            + fmaxf(fmaf(ay, inv, bb.y), 0.f) * cw.y
            + fmaxf(fmaf(az, inv, bb.z), 0.f) * cw.z
            + fmaxf(fmaf(aw, inv, bb.w), 0.f) * cw.w;
#pragma unroll
    for (int off = 1; off <= 8; off <<= 1) p += __shfl_xor(p, off, 64);
    if (lane == 0) out[d] = p + clsB[0];
}

extern "C" void kernel_launch(void* const* d_in, const int* in_sizes, int n_in,
                              void* d_out, int out_size, void* d_ws, size_t ws_size,
                              hipStream_t stream) {
    const float* x     = (const float*)d_in[0];
    const int*   ei    = (const int*)d_in[1];
    const float* projW = (const float*)d_in[2];
    const float* projB = (const float*)d_in[3];
    const float* W1    = (const float*)d_in[4];
    const float* as1w  = (const float*)d_in[5];
    const float* ad1w  = (const float*)d_in[6];
    const float* b1    = (const float*)d_in[7];
    const float* W2    = (const float*)d_in[8];
    const float* as2w  = (const float*)d_in[9];
    const float* ad2w  = (const float*)d_in[10];
    const float* b2    = (const float*)d_in[11];
    const float* clsW  = (const float*)d_in[12];
    const float* clsB  = (const float*)d_in[13];
    float* out = (float*)d_out;

    const int N = in_sizes[0] / F_IN;
    const int E = in_sizes[1] / 2;

    char* ws = (char*)d_ws;
    size_t off = 0;
    auto alloc = [&](size_t bytes) -> void* {
        void* p = ws + off;
        off += (bytes + 255) & ~(size_t)255;
        return p;
    };
    float* h0     = (float*)alloc((size_t)N * 64 * 4);   // reused as h2lin
    float* h1     = (float*)alloc((size_t)N * 256 * 4);
    float* as1    = (float*)alloc((size_t)N * 4 * 4);
    float* ad1    = (float*)alloc((size_t)N * 4 * 4);
    float* as2    = (float*)alloc((size_t)N * 4);
    float* ad2    = (float*)alloc((size_t)N * 4);
    int*   dc     = (int*)alloc((size_t)2 * N * 4);      // deg | cursor adjacent
    int*   deg    = dc;
    int*   cursor = dc + N;
    int*   rowptr = (int*)alloc((size_t)(N + 1) * 4);
    int*   parts  = (int*)alloc(1024 * 4);
    int*   csrc   = (int*)alloc((size_t)E * 4);
    float* wt0    = (float*)alloc(64 * KP_PROJ * 4);
    float* wt2    = (float*)alloc(64 * 256 * 4);
    float* va     = (float*)alloc(512 * 4);
    float* h2lin  = h0;

    // weight transposes + va vectors + deg/cursor zeroing (one dispatch)
    const int ntr = 64 * KP_PROJ + 64 * 256 + 512 + 2 * N;
    k_trans<<<(ntr + 255) / 256, 256, 0, stream>>>(
        projW, W2, W1, as1w, ad1w, wt0, wt2, va, dc, 2 * N);

    // CSR build (real edges only; self-loops inline in aggregation kernels)
    k_deg<<<1024, 256, 0, stream>>>(ei, E, deg);
    int nblk = (N + 1023) / 1024;
    k_scan_part<<<nblk, 1024, 0, stream>>>(deg, rowptr, parts, N);
    k_scan_small<<<1, 64, 0, stream>>>(parts, nblk);
    k_scan_add<<<nblk, 1024, 0, stream>>>(rowptr, parts, N, E);
    k_scatter<<<1024, 256, 0, stream>>>(ei, E, rowptr, cursor, csrc);

    // MLP in (+ fused as1/ad1 reduction)
    k_proj<<<(N + 31) / 32, 256, 0, stream>>>(x, wt0, projB, va, h0, as1, ad1, N);

    // GAT layer 1 (h0-domain aggregation, edge weights inline, 8 dst/block)
    k_gat1f<<<(N + 7) / 8, 512, 0, stream>>>(h0, as1, ad1, rowptr, csrc, W1, b1, h1, N);

    // GAT layer 2 + classifier (edge weights fused into k_gat2)
    k_lin2<<<(N + 31) / 32, 256, 0, stream>>>(h1, wt2, as2w, ad2w, h2lin, as2, ad2, N);
    k_gat2<<<(N + 3) / 4, 256, 0, stream>>>(h2lin, as2, ad2, rowptr, csrc, b2,
                                            clsW, clsB, out, N);
}

// Round 17
// 303.715 us; speedup vs baseline: 1.1453x; 1.0254x over previous
//
#include <hip/hip_runtime.h>

#define F_IN 165
#define KP_PROJ 168
constexpr float NEG_SLOPE = 0.2f;

// lrelu(z) = max(z, 0.2z) -- 2 VALU inst vs 3 for cmp/cndmask form.
__device__ __forceinline__ float lrelu(float z) { return fmaxf(z, NEG_SLOPE * z); }

// ---- weight transposes + va vectors + workspace zeroing ---------------------
__global__ void k_trans(const float* __restrict__ pw, const float* __restrict__ w2,
                        const float* __restrict__ w1, const float* __restrict__ as1w,
                        const float* __restrict__ ad1w,
                        float* __restrict__ t0, float* __restrict__ t2,
                        float* __restrict__ va, int* __restrict__ dc, int ndc) {
    int i = blockIdx.x * 256 + threadIdx.x;
    const int n0 = 64 * KP_PROJ, n2 = 64 * 256;
    if (i < n0) {
        int c = i / KP_PROJ, r = i - c * KP_PROJ;
        t0[i] = (r < F_IN) ? pw[r * 64 + c] : 0.f;
    } else if (i < n0 + n2) {
        int j = i - n0; int c = j >> 8, r = j & 255;
        t2[j] = w2[r * 64 + c];
    } else if (i < n0 + n2 + 512) {
        int j = i - n0 - n2;          // 0..511
        int i2 = j >> 6;              // 0..7 = plane*4 + h
        int plane = i2 >> 2, h = i2 & 3, k = j & 63;
        const float* att = plane ? ad1w : as1w;
        float acc = 0.f;
        for (int c = 0; c < 64; ++c)
            acc = fmaf(w1[k * 256 + h * 64 + c], att[h * 64 + c], acc);
        va[j] = acc;
    }
    int z = i - (n0 + n2 + 512);
    if (z >= 0 && z < ndc) dc[z] = 0;
}

// ---- h0 = relu(x @ W + b) + fused as1/ad1 via single-wave LDS transpose -----
__global__ void k_proj(const float* __restrict__ x, const float* __restrict__ Wt,
                       const float* __restrict__ b, const float* __restrict__ va,
                       float* __restrict__ h0, float* __restrict__ as_,
                       float* __restrict__ ad_, int N) {
    __shared__ float xs[32][KP_PROJ];
    __shared__ float vas[8][65];
    __shared__ float hrow[4][64];
    int base = blockIdx.x * 32;
    int t = threadIdx.x;
    for (int idx = t; idx < 512; idx += 256)
        vas[idx >> 6][idx & 63] = va[idx];
    for (int idx = t; idx < 32 * KP_PROJ; idx += 256) {
        int nl = idx / KP_PROJ, k = idx - nl * KP_PROJ;
        int node = base + nl;
        xs[nl][k] = (node < N && k < F_IN) ? x[(size_t)node * F_IN + k] : 0.f;
    }
    __syncthreads();
    int g = t >> 6, col = t & 63;
    float acc[8];
    float bb = b[col];
#pragma unroll
    for (int m = 0; m < 8; ++m) acc[m] = bb;
    const float* wrow = Wt + col * KP_PROJ;
    for (int k4 = 0; k4 < KP_PROJ / 4; ++k4) {
        float4 wv = *(const float4*)(wrow + k4 * 4);
#pragma unroll
        for (int m = 0; m < 8; ++m) {
            float4 av = *(const float4*)&xs[g * 8 + m][k4 * 4];
            acc[m] = fmaf(av.x, wv.x, acc[m]);
            acc[m] = fmaf(av.y, wv.y, acc[m]);
            acc[m] = fmaf(av.z, wv.z, acc[m]);
            acc[m] = fmaf(av.w, wv.w, acc[m]);
        }
    }
    int i8 = col & 7, c8 = col >> 3;
    const float* vbase = &vas[i8][c8 * 8];
    const float* hbase = &hrow[g][c8 * 8];
#pragma unroll
    for (int m = 0; m < 8; ++m) {
        int node = base + g * 8 + m;
        float h = fmaxf(acc[m], 0.f);
        if (node < N) h0[(size_t)node * 64 + col] = h;
        hrow[g][col] = h;            // wave-private LDS, wave-synchronous use
        float r = 0.f;
#pragma unroll
        for (int e = 0; e < 8; ++e)
            r = fmaf(hbase[e], vbase[e], r);
        r += __shfl_xor(r, 8, 64);
        r += __shfl_xor(r, 16, 64);
        r += __shfl_xor(r, 32, 64);
        if (node < N && col < 8) {
            if (col < 4) as_[(size_t)node * 4 + col] = r;
            else         ad_[(size_t)node * 4 + (col - 4)] = r;
        }
    }
}

// ---- h2lin = h1 @ W2: Wt2[64][256], 32 nodes/block, 4 groups x 8, fused att -
__global__ void k_lin2(const float* __restrict__ h1, const float* __restrict__ Wt,
                       const float* __restrict__ att_s, const float* __restrict__ att_d,
                       float* __restrict__ out, float* __restrict__ as_,
                       float* __restrict__ ad_, int N) {
    __shared__ float hs[32][256];
    int base = blockIdx.x * 32;
    int t = threadIdx.x;
    for (int i = 0; i < 8; ++i) {
        int idx4 = t + i * 256;
        int nl = idx4 >> 6, k4 = idx4 & 63;
        int node = base + nl;
        float4 v = make_float4(0.f, 0.f, 0.f, 0.f);
        if (node < N) v = *(const float4*)(h1 + (size_t)node * 256 + k4 * 4);
        *(float4*)&hs[nl][k4 * 4] = v;
    }
    __syncthreads();
    int g = t >> 6, col = t & 63;
    float acc[8] = {};
    const float* wrow = Wt + col * 256;
    for (int k4 = 0; k4 < 64; ++k4) {
        float4 wv = *(const float4*)(wrow + k4 * 4);
#pragma unroll
        for (int m = 0; m < 8; ++m) {
            float4 av = *(const float4*)&hs[g * 8 + m][k4 * 4];
            acc[m] = fmaf(av.x, wv.x, acc[m]);
            acc[m] = fmaf(av.y, wv.y, acc[m]);
            acc[m] = fmaf(av.z, wv.z, acc[m]);
            acc[m] = fmaf(av.w, wv.w, acc[m]);
        }
    }
    float sw = att_s[col], dw = att_d[col];
#pragma unroll
    for (int m = 0; m < 8; ++m) {
        int node = base + g * 8 + m;
        if (node < N) out[(size_t)node * 64 + col] = acc[m];
        float sv = acc[m] * sw, dv = acc[m] * dw;
#pragma unroll
        for (int off = 32; off; off >>= 1) {
            sv += __shfl_xor(sv, off, 64);
            dv += __shfl_xor(dv, off, 64);
        }
        if (col == 0 && node < N) { as_[node] = sv; ad_[node] = dv; }
    }
}

// ------- CSR build over REAL edges only (self-loops handled inline) ----------
__global__ void k_deg(const int* __restrict__ ei, int E, int* __restrict__ deg) {
    for (int i = blockIdx.x * blockDim.x + threadIdx.x; i < E; i += gridDim.x * blockDim.x) {
        atomicAdd(&deg[ei[E + i]], 1);
    }
}

__global__ void k_scan_part(const int* __restrict__ deg, int* __restrict__ out,
                            int* __restrict__ partials, int n) {
    __shared__ int tmp[1024];
    int b = blockIdx.x, t = threadIdx.x;
    int i = b * 1024 + t;
    int v = (i < n) ? deg[i] : 0;
    tmp[t] = v;
    __syncthreads();
    for (int off = 1; off < 1024; off <<= 1) {
        int xval = (t >= off) ? tmp[t - off] : 0;
        __syncthreads();
        tmp[t] += xval;
        __syncthreads();
    }
    if (i < n) out[i] = tmp[t] - v; // exclusive
    if (t == 1023) partials[b] = tmp[t];
}

__global__ void k_scan_small(int* __restrict__ partials, int nblk) {
    int lane = threadIdx.x & 63;
    int carry = 0;
    for (int base = 0; base < nblk; base += 64) {
        int idx = base + lane;
        int v = (idx < nblk) ? partials[idx] : 0;
        int orig = v;
#pragma unroll
        for (int off = 1; off < 64; off <<= 1) {
            int u = __shfl_up(v, off, 64);
            if (lane >= off) v += u;
        }
        if (idx < nblk) partials[idx] = carry + v - orig; // exclusive
        carry += __shfl(v, 63, 64);
    }
}

__global__ void k_scan_add(int* __restrict__ rowptr, const int* __restrict__ partials,
                           int n, int total) {
    int i = blockIdx.x * 1024 + threadIdx.x;
    if (i < n) rowptr[i] += partials[blockIdx.x];
    if (i == 0) rowptr[n] = total;
}

__global__ void k_scatter(const int* __restrict__ ei, int E,
                          const int* __restrict__ rowptr, int* __restrict__ cursor,
                          int* __restrict__ csrc) {
    for (int i = blockIdx.x * blockDim.x + threadIdx.x; i < E; i += gridDim.x * blockDim.x) {
        int src = ei[i], dst = ei[E + i];
        int pos = rowptr[dst] + atomicAdd(&cursor[dst], 1);
        csrc[pos] = src;
    }
}

// --------- GAT layer 1 fused: inline edge weights + h0 agg + W1 GEMM ---------
// 4 dsts/block (256 thr, r14-proven faster than 8-dst). Phase 1: 4 slots x 16
// lanes, 2 edges in flight per slot (8 independent gather chains per wave).
// Phase 2: scalar W1 + scalar LDS (r10/r12 proven). Do NOT vectorize (spills
// r4/5/9), pin unroll 1 (r11), or transpose agg (r13 bank conflicts).
__global__ void k_gat1f(const float* __restrict__ h0, const float* __restrict__ as1,
                        const float* __restrict__ ad1, const int* __restrict__ rowptr,
                        const int* __restrict__ csrc, const float* __restrict__ W1,
                        const float* __restrict__ b1, float* __restrict__ h1out, int N) {
    __shared__ float agg[4][256];
    int t = threadIdx.x, wv = t >> 6, lane = t & 63;
    int slot = lane >> 4, sl = lane & 15;
    int d = blockIdx.x * 4 + wv;
    if (d < N) {
        int s0 = rowptr[d], e0 = rowptr[d + 1];
        float4 ad = *(const float4*)(ad1 + (size_t)d * 4);
        float a00=0,a01=0,a02=0,a03=0;
        float a10=0,a11=0,a12=0,a13=0;
        float a20=0,a21=0,a22=0,a23=0;
        float a30=0,a31=0,a32=0,a33=0;
        float d0=0,d1=0,d2=0,d3=0;
        const float* hb = h0 + sl * 4;
        if (slot == 0) {
            // self-loop
            float4 a = *(const float4*)(as1 + (size_t)d * 4);
            float wx = __expf(lrelu(a.x + ad.x));
            float wy = __expf(lrelu(a.y + ad.y));
            float wz = __expf(lrelu(a.z + ad.z));
            float ww = __expf(lrelu(a.w + ad.w));
            float4 hv = *(const float4*)(hb + (size_t)d * 64);
            a00 = wx*hv.x; a01 = wx*hv.y; a02 = wx*hv.z; a03 = wx*hv.w;
            a10 = wy*hv.x; a11 = wy*hv.y; a12 = wy*hv.z; a13 = wy*hv.w;
            a20 = wz*hv.x; a21 = wz*hv.y; a22 = wz*hv.z; a23 = wz*hv.w;
            a30 = ww*hv.x; a31 = ww*hv.y; a32 = ww*hv.z; a33 = ww*hv.w;
            d0 = wx; d1 = wy; d2 = wz; d3 = ww;
        }
        int j = s0 + slot;
        for (; j + 4 < e0; j += 8) {
            int sA = csrc[j], sB = csrc[j + 4];
            float4 aA = *(const float4*)(as1 + (size_t)sA * 4);
            float4 aB = *(const float4*)(as1 + (size_t)sB * 4);
            float4 hA = *(const float4*)(hb + (size_t)sA * 64);
            float4 hB = *(const float4*)(hb + (size_t)sB * 64);
            float wxA = __expf(lrelu(aA.x + ad.x));
            float wyA = __expf(lrelu(aA.y + ad.y));
            float wzA = __expf(lrelu(aA.z + ad.z));
            float wwA = __expf(lrelu(aA.w + ad.w));
            float wxB = __expf(lrelu(aB.x + ad.x));
            float wyB = __expf(lrelu(aB.y + ad.y));
            float wzB = __expf(lrelu(aB.z + ad.z));
            float wwB = __expf(lrelu(aB.w + ad.w));
            a00 = fmaf(wxA, hA.x, a00); a01 = fmaf(wxA, hA.y, a01);
            a02 = fmaf(wxA, hA.z, a02); a03 = fmaf(wxA, hA.w, a03);
            a10 = fmaf(wyA, hA.x, a10); a11 = fmaf(wyA, hA.y, a11);
            a12 = fmaf(wyA, hA.z, a12); a13 = fmaf(wyA, hA.w, a13);
            a20 = fmaf(wzA, hA.x, a20); a21 = fmaf(wzA, hA.y, a21);
            a22 = fmaf(wzA, hA.z, a22); a23 = fmaf(wzA, hA.w, a23);
            a30 = fmaf(wwA, hA.x, a30); a31 = fmaf(wwA, hA.y, a31);
            a32 = fmaf(wwA, hA.z, a32); a33 = fmaf(wwA, hA.w, a33);
            d0 += wxA; d1 += wyA; d2 += wzA; d3 += wwA;
            a00 = fmaf(wxB, hB.x, a00); a01 = fmaf(wxB, hB.y, a01);
            a02 = fmaf(wxB, hB.z, a02); a03 = fmaf(wxB, hB.w, a03);
            a10 = fmaf(wyB, hB.x, a10); a11 = fmaf(wyB, hB.y, a11);
            a12 = fmaf(wyB, hB.z, a12); a13 = fmaf(wyB, hB.w, a13);
            a20 = fmaf(wzB, hB.x, a20); a21 = fmaf(wzB, hB.y, a21);
            a22 = fmaf(wzB, hB.z, a22); a23 = fmaf(wzB, hB.w, a23);
            a30 = fmaf(wwB, hB.x, a30); a31 = fmaf(wwB, hB.y, a31);
            a32 = fmaf(wwB, hB.z, a32); a33 = fmaf(wwB, hB.w, a33);
            d0 += wxB; d1 += wyB; d2 += wzB; d3 += wwB;
        }
        if (j < e0) {
            int s = csrc[j];
            float4 a = *(const float4*)(as1 + (size_t)s * 4);
            float4 hv = *(const float4*)(hb + (size_t)s * 64);
            float wx = __expf(lrelu(a.x + ad.x));
            float wy = __expf(lrelu(a.y + ad.y));
            float wz = __expf(lrelu(a.z + ad.z));
            float ww = __expf(lrelu(a.w + ad.w));
            a00 = fmaf(wx, hv.x, a00); a01 = fmaf(wx, hv.y, a01);
            a02 = fmaf(wx, hv.z, a02); a03 = fmaf(wx, hv.w, a03);
            a10 = fmaf(wy, hv.x, a10); a11 = fmaf(wy, hv.y, a11);
            a12 = fmaf(wy, hv.z, a12); a13 = fmaf(wy, hv.w, a13);
            a20 = fmaf(wz, hv.x, a20); a21 = fmaf(wz, hv.y, a21);
            a22 = fmaf(wz, hv.z, a22); a23 = fmaf(wz, hv.w, a23);
            a30 = fmaf(ww, hv.x, a30); a31 = fmaf(ww, hv.y, a31);
            a32 = fmaf(ww, hv.z, a32); a33 = fmaf(ww, hv.w, a33);
            d0 += wx; d1 += wy; d2 += wz; d3 += ww;
        }
#pragma unroll
        for (int off = 16; off <= 32; off <<= 1) {
            a00 += __shfl_xor(a00, off, 64); a01 += __shfl_xor(a01, off, 64);
            a02 += __shfl_xor(a02, off, 64); a03 += __shfl_xor(a03, off, 64);
            a10 += __shfl_xor(a10, off, 64); a11 += __shfl_xor(a11, off, 64);
            a12 += __shfl_xor(a12, off, 64); a13 += __shfl_xor(a13, off, 64);
            a20 += __shfl_xor(a20, off, 64); a21 += __shfl_xor(a21, off, 64);
            a22 += __shfl_xor(a22, off, 64); a23 += __shfl_xor(a23, off, 64);
            a30 += __shfl_xor(a30, off, 64); a31 += __shfl_xor(a31, off, 64);
            a32 += __shfl_xor(a32, off, 64); a33 += __shfl_xor(a33, off, 64);
            d0  += __shfl_xor(d0,  off, 64); d1  += __shfl_xor(d1,  off, 64);
            d2  += __shfl_xor(d2,  off, 64); d3  += __shfl_xor(d3,  off, 64);
        }
        if (slot == 0) {
            float i0 = 1.f / d0, i1 = 1.f / d1, i2 = 1.f / d2, i3 = 1.f / d3;
            *(float4*)&agg[wv][  0 + sl * 4] = make_float4(a00*i0, a01*i0, a02*i0, a03*i0);
            *(float4*)&agg[wv][ 64 + sl * 4] = make_float4(a10*i1, a11*i1, a12*i1, a13*i1);
            *(float4*)&agg[wv][128 + sl * 4] = make_float4(a20*i2, a21*i2, a22*i2, a23*i2);
            *(float4*)&agg[wv][192 + sl * 4] = make_float4(a30*i3, a31*i3, a32*i3, a33*i3);
        }
    }
    __syncthreads();
    int h = t >> 6;
    float o0 = 0.f, o1 = 0.f, o2 = 0.f, o3 = 0.f;
    for (int k = 0; k < 64; ++k) {
        float wv1 = W1[k * 256 + t];
        o0 = fmaf(agg[0][h * 64 + k], wv1, o0);
        o1 = fmaf(agg[1][h * 64 + k], wv1, o1);
        o2 = fmaf(agg[2][h * 64 + k], wv1, o2);
        o3 = fmaf(agg[3][h * 64 + k], wv1, o3);
    }
    float bb = b1[t];
    int base = blockIdx.x * 4;
    if (base + 0 < N) h1out[(size_t)(base + 0) * 256 + t] = fmaxf(o0 + bb, 0.f);
    if (base + 1 < N) h1out[(size_t)(base + 1) * 256 + t] = fmaxf(o1 + bb, 0.f);
    if (base + 2 < N) h1out[(size_t)(base + 2) * 256 + t] = fmaxf(o2 + bb, 0.f);
    if (base + 3 < N) h1out[(size_t)(base + 3) * 256 + t] = fmaxf(o3 + bb, 0.f);
}

// --------- GAT layer 2 (1 head): wave per dst, 2-edge ILP, fused classifier --
__global__ void k_gat2(const float* __restrict__ hlin, const float* __restrict__ as2,
                       const float* __restrict__ ad2, const int* __restrict__ rowptr,
                       const int* __restrict__ csrc, const float* __restrict__ bias,
                       const float* __restrict__ clsW, const float* __restrict__ clsB,
                       float* __restrict__ out, int N) {
    int t = threadIdx.x, wv = t >> 6, lane = t & 63;
    int slot = lane >> 4, sl = lane & 15;
    int d = blockIdx.x * 4 + wv;
    if (d >= N) return;
    int s0 = rowptr[d], e0 = rowptr[d + 1];
    float add = ad2[d];
    float ax = 0.f, ay = 0.f, az = 0.f, aw = 0.f, den = 0.f;
    const float* hb = hlin + sl * 4;
    if (slot == 0) {   // self-loop
        float w = __expf(lrelu(as2[d] + add));
        float4 hv = *(const float4*)(hb + (size_t)d * 64);
        ax = w * hv.x; ay = w * hv.y; az = w * hv.z; aw = w * hv.w;
        den = w;
    }
    int j = s0 + slot;
    for (; j + 4 < e0; j += 8) {
        int sA = csrc[j], sB = csrc[j + 4];
        float wA = __expf(lrelu(as2[sA] + add));
        float wB = __expf(lrelu(as2[sB] + add));
        float4 hA = *(const float4*)(hb + (size_t)sA * 64);
        float4 hB = *(const float4*)(hb + (size_t)sB * 64);
        ax = fmaf(wA, hA.x, ax); ay = fmaf(wA, hA.y, ay);
        az = fmaf(wA, hA.z, az); aw = fmaf(wA, hA.w, aw);
        den += wA;
        ax = fmaf(wB, hB.x, ax); ay = fmaf(wB, hB.y, ay);
        az = fmaf(wB, hB.z, az); aw = fmaf(wB, hB.w, aw);
        den += wB;
    }
    if (j < e0) {
        int s = csrc[j];
        float w = __expf(lrelu(as2[s] + add));
        float4 hv = *(const float4*)(hb + (size_t)s * 64);
        ax = fmaf(w, hv.x, ax); ay = fmaf(w, hv.y, ay);
        az = fmaf(w, hv.z, az); aw = fmaf(w, hv.w, aw);
        den += w;
    }
#pragma unroll
    for (int off = 16; off <= 32; off <<= 1) {
        ax += __shfl_xor(ax, off, 64); ay += __shfl_xor(ay, off, 64);
        az += __shfl_xor(az, off, 64); aw += __shfl_xor(aw, off, 64);
        den += __shfl_xor(den, off, 64);
    }
    float inv = 1.f / den;
    float4 bb = *(const float4*)(bias + sl * 4);
    float4 cw = *(const float4*)(clsW + sl * 4);
    float p = fmaxf(fmaf(ax, inv, bb.x), 0.f) * cw.x
            + fmaxf(fmaf(ay, inv, bb.y), 0.f) * cw.y
            + fmaxf(fmaf(az, inv, bb.z), 0.f) * cw.z
            + fmaxf(fmaf(aw, inv, bb.w), 0.f) * cw.w;
#pragma unroll
    for (int off = 1; off <= 8; off <<= 1) p += __shfl_xor(p, off, 64);
    if (lane == 0) out[d] = p + clsB[0];
}

extern "C" void kernel_launch(void* const* d_in, const int* in_sizes, int n_in,
                              void* d_out, int out_size, void* d_ws, size_t ws_size,
                              hipStream_t stream) {
    const float* x     = (const float*)d_in[0];
    const int*   ei    = (const int*)d_in[1];
    const float* projW = (const float*)d_in[2];
    const float* projB = (const float*)d_in[3];
    const float* W1    = (const float*)d_in[4];
    const float* as1w  = (const float*)d_in[5];
    const float* ad1w  = (const float*)d_in[6];
    const float* b1    = (const float*)d_in[7];
    const float* W2    = (const float*)d_in[8];
    const float* as2w  = (const float*)d_in[9];
    const float* ad2w  = (const float*)d_in[10];
    const float* b2    = (const float*)d_in[11];
    const float* clsW  = (const float*)d_in[12];
    const float* clsB  = (const float*)d_in[13];
    float* out = (float*)d_out;

    const int N = in_sizes[0] / F_IN;
    const int E = in_sizes[1] / 2;

    char* ws = (char*)d_ws;
    size_t off = 0;
    auto alloc = [&](size_t bytes) -> void* {
        void* p = ws + off;
        off += (bytes + 255) & ~(size_t)255;
        return p;
    };
    float* h0     = (float*)alloc((size_t)N * 64 * 4);   // reused as h2lin
    float* h1     = (float*)alloc((size_t)N * 256 * 4);
    float* as1    = (float*)alloc((size_t)N * 4 * 4);
    float* ad1    = (float*)alloc((size_t)N * 4 * 4);
    float* as2    = (float*)alloc((size_t)N * 4);
    float* ad2    = (float*)alloc((size_t)N * 4);
    int*   dc     = (int*)alloc((size_t)2 * N * 4);      // deg | cursor adjacent
    int*   deg    = dc;
    int*   cursor = dc + N;
    int*   rowptr = (int*)alloc((size_t)(N + 1) * 4);
    int*   parts  = (int*)alloc(1024 * 4);
    int*   csrc   = (int*)alloc((size_t)E * 4);
    float* wt0    = (float*)alloc(64 * KP_PROJ * 4);
    float* wt2    = (float*)alloc(64 * 256 * 4);
    float* va     = (float*)alloc(512 * 4);
    float* h2lin  = h0;

    // weight transposes + va vectors + deg/cursor zeroing (one dispatch)
    const int ntr = 64 * KP_PROJ + 64 * 256 + 512 + 2 * N;
    k_trans<<<(ntr + 255) / 256, 256, 0, stream>>>(
        projW, W2, W1, as1w, ad1w, wt0, wt2, va, dc, 2 * N);

    // CSR build (real edges only; self-loops inline in aggregation kernels)
    k_deg<<<1024, 256, 0, stream>>>(ei, E, deg);
    int nblk = (N + 1023) / 1024;
    k_scan_part<<<nblk, 1024, 0, stream>>>(deg, rowptr, parts, N);
    k_scan_small<<<1, 64, 0, stream>>>(parts, nblk);
    k_scan_add<<<nblk, 1024, 0, stream>>>(rowptr, parts, N, E);
    k_scatter<<<1024, 256, 0, stream>>>(ei, E, rowptr, cursor, csrc);

    // MLP in (+ fused as1/ad1 reduction)
    k_proj<<<(N + 31) / 32, 256, 0, stream>>>(x, wt0, projB, va, h0, as1, ad1, N);

    // GAT layer 1 (h0-domain aggregation, edge weights inline, 4 dst/block)
    k_gat1f<<<(N + 3) / 4, 256, 0, stream>>>(h0, as1, ad1, rowptr, csrc, W1, b1, h1, N);

    // GAT layer 2 + classifier (edge weights fused into k_gat2)
    k_lin2<<<(N + 31) / 32, 256, 0, stream>>>(h1, wt2, as2w, ad2w, h2lin, as2, ad2, N);
    k_gat2<<<(N + 3) / 4, 256, 0, stream>>>(h2lin, as2, ad2, rowptr, csrc, b2,
                                            clsW, clsB, out, N);
}